// Round 4
// baseline (2285.129 us; speedup 1.0000x reference)
//
#include <hip/hip_runtime.h>
#include <hip/hip_bf16.h>

typedef __attribute__((ext_vector_type(8))) short short8;
typedef __attribute__((ext_vector_type(8))) unsigned short ushort8;
typedef __attribute__((ext_vector_type(4))) float f32x4;

#define NROWS 131072L   // N*T = 4096*32

__device__ __forceinline__ unsigned short f2bfu(float f) {
  union { float f; unsigned u; } a; a.f = f;
  unsigned r = a.u + 0x7fffu + ((a.u >> 16) & 1u);
  return (unsigned short)(r >> 16);
}
__device__ __forceinline__ float bfu2f(unsigned short u) {
  union { unsigned u; float f; } a; a.u = (unsigned)u << 16; return a.f;
}

__device__ __forceinline__ void llds16(const void* g, void* l) {
  __builtin_amdgcn_global_load_lds(
      (const __attribute__((address_space(1))) void*)g,
      (__attribute__((address_space(3))) void*)l, 16, 0, 0);
}

// ---------------------------------------------------------------------------
// GEMM: C[M,N] = A[M,K] (bf16) * B[N,K]^T (bf16) + bias (+resid bf16) (relu?)
// m97 structure: 128x128 tile, BK=64, 4 waves (2x2 of 64x64), 16x16x32 MFMA.
// grid = (N/128, M/128). Output bf16. XCD-chunked block swizzle (T1, m204
// bijective variant) so N-tiles sharing an A-panel land on one XCD's L2.
// ---------------------------------------------------------------------------
template<bool RELU, bool RESID>
__global__ __launch_bounds__(256) void gemm_bt(
    const unsigned short* __restrict__ A, const unsigned short* __restrict__ B,
    const float* __restrict__ bias, const unsigned short* __restrict__ resid,
    unsigned short* __restrict__ Cb, int N, int K)
{
  __shared__ unsigned short lds_a[128 * 64];
  __shared__ unsigned short lds_b[128 * 64];
  const int tid  = threadIdx.x;
  const int lane = tid & 63;
  const int wave = tid >> 6;
  const int wr = wave >> 1, wc = wave & 1;

  // XCD-aware bijective swizzle (m204): dispatch id -> chunked tile id
  const int gx  = gridDim.x;
  const int nwg = gx * gridDim.y;
  int bid = blockIdx.y * gx + blockIdx.x;
  {
    const int q = nwg >> 3, r = nwg & 7;
    const int xcd = bid & 7, i = bid >> 3;
    bid = (xcd < r ? xcd * (q + 1) : r * (q + 1) + (xcd - r) * q) + i;
  }
  const long brow = (long)(bid / gx) * 128;
  const long bcol = (long)(bid % gx) * 128;

  f32x4 acc[4][4];
#pragma unroll
  for (int m = 0; m < 4; ++m)
#pragma unroll
    for (int n = 0; n < 4; ++n)
      acc[m][n] = (f32x4){0.f, 0.f, 0.f, 0.f};

  const int srow = tid >> 3;        // 0..31
  const int scol = (tid & 7) * 8;   // 0..56

  for (int k0 = 0; k0 < K; k0 += 64) {
#pragma unroll
    for (int i = 0; i < 4; ++i) {
      int r = i * 32 + srow;
      llds16(A + (brow + r) * (long)K + k0 + scol, lds_a + r * 64 + scol);
    }
#pragma unroll
    for (int i = 0; i < 4; ++i) {
      int r = i * 32 + srow;
      llds16(B + (bcol + r) * (long)K + k0 + scol, lds_b + r * 64 + scol);
    }
    asm volatile("s_waitcnt vmcnt(0)" ::: "memory");
    __syncthreads();

#pragma unroll
    for (int ks = 0; ks < 2; ++ks) {
      short8 af[4], bfr[4];
#pragma unroll
      for (int m = 0; m < 4; ++m)
        af[m] = *(const short8*)(lds_a + (wr*64 + m*16 + (lane & 15))*64 + ks*32 + (lane >> 4)*8);
#pragma unroll
      for (int n = 0; n < 4; ++n)
        bfr[n] = *(const short8*)(lds_b + (wc*64 + n*16 + (lane & 15))*64 + ks*32 + (lane >> 4)*8);
#pragma unroll
      for (int m = 0; m < 4; ++m)
#pragma unroll
        for (int n = 0; n < 4; ++n)
          acc[m][n] = __builtin_amdgcn_mfma_f32_16x16x32_bf16(af[m], bfr[n], acc[m][n], 0, 0, 0);
    }
    __syncthreads();
  }

  const int fr = lane & 15;
  const int fq = lane >> 4;
#pragma unroll
  for (int m = 0; m < 4; ++m) {
#pragma unroll
    for (int n = 0; n < 4; ++n) {
      long col = bcol + wc*64 + n*16 + fr;
      float bv = bias[col];
#pragma unroll
      for (int r2 = 0; r2 < 4; ++r2) {
        long row = brow + wr*64 + m*16 + fq*4 + r2;
        float v = acc[m][n][r2] + bv;
        if (RESID) v += bfu2f(resid[row * N + col]);
        if (RELU)  v = fmaxf(v, 0.f);
        Cb[row * N + col] = f2bfu(v);
      }
    }
  }
}

// ---------------------------------------------------------------------------
// Fused weight prep: bf16-convert + concat/pad all weights in ONE kernel.
// Virtual layout: [Wqkv 640*768][bqkv 640][Wp 147456][W1 1572864][W2 1572864]
// Wqkv row order: q1 k1 v1 q2 k2 v2 (96 rows each) + 64 zero rows.
// ---------------------------------------------------------------------------
__global__ __launch_bounds__(256) void prep_kernel(
    const float* __restrict__ Wq1, const float* __restrict__ Wk1, const float* __restrict__ Wv1,
    const float* __restrict__ Wq2, const float* __restrict__ Wk2, const float* __restrict__ Wv2,
    const float* __restrict__ bq1, const float* __restrict__ bk1, const float* __restrict__ bv1,
    const float* __restrict__ bq2, const float* __restrict__ bk2, const float* __restrict__ bv2,
    const float* __restrict__ Wp, const float* __restrict__ W1, const float* __restrict__ W2,
    unsigned short* __restrict__ Wqkv, float* __restrict__ bqkv,
    unsigned short* __restrict__ Wp_b, unsigned short* __restrict__ W1_b,
    unsigned short* __restrict__ W2_b)
{
  long i = (long)blockIdx.x * 256 + threadIdx.x;
  if (i >= 3785344L) return;
  if (i < 491520) {
    int row = (int)(i / 768), col = (int)(i % 768);
    float v = 0.f;
    if (row < 576) {
      int which = row / 96, r = row % 96;
      const float* s = which == 0 ? Wq1 : which == 1 ? Wk1 : which == 2 ? Wv1
                     : which == 3 ? Wq2 : which == 4 ? Wk2 : Wv2;
      v = s[r * 768 + col];
    }
    Wqkv[i] = f2bfu(v);
    return;
  }
  i -= 491520;
  if (i < 640) {
    float v = 0.f;
    if (i < 576) {
      int which = (int)(i / 96), r = (int)(i % 96);
      const float* s = which == 0 ? bq1 : which == 1 ? bk1 : which == 2 ? bv1
                     : which == 3 ? bq2 : which == 4 ? bk2 : bv2;
      v = s[r];
    }
    bqkv[i] = v;
    return;
  }
  i -= 640;
  if (i < 147456) { Wp_b[i] = f2bfu(Wp[i]); return; }
  i -= 147456;
  if (i < 1572864) { W1_b[i] = f2bfu(W1[i]); return; }
  i -= 1572864;
  W2_b[i] = f2bfu(W2[i]);
}

// ---------------------------------------------------------------------------
// embed: xb = bf16(emb[ids] + pos). Local rows; chunk offset applied on host.
// 4 rows/block, 1 wave/row. row&31 == position-in-sequence (chunk R % 32 == 0).
// ---------------------------------------------------------------------------
__global__ __launch_bounds__(256) void embed_kernel(
    const int* __restrict__ ids, const float* __restrict__ emb,
    const float* __restrict__ pos, unsigned short* __restrict__ xb)
{
  const long row  = (long)blockIdx.x * 4 + (threadIdx.x >> 6);
  const int lane = threadIdx.x & 63;
  const int tok  = ids[row];
  const int tp   = (int)(row & 31);
  const float4* e = (const float4*)(emb + (size_t)tok * 768);
  const float4* p = (const float4*)(pos + (size_t)tp * 768);
  ushort4* bo = (ushort4*)(xb + row * 768);
#pragma unroll
  for (int j = 0; j < 3; ++j) {
    int idx = j * 64 + lane;
    float4 v = e[idx];
    float4 q = p[idx];
    v.x += q.x; v.y += q.y; v.z += q.z; v.w += q.w;
    ushort4 u;
    u.x = f2bfu(v.x); u.y = f2bfu(v.y); u.z = f2bfu(v.z); u.w = f2bfu(v.w);
    bo[idx] = u;
  }
}

// ---------------------------------------------------------------------------
// attention: one block per (seq, head). qkv bf16 [rows][640],
// row cols: [q1 k1 v1 q2 k2 v2 pad64] each 96.  z out bf16 [rows][192].
// ---------------------------------------------------------------------------
__global__ __launch_bounds__(256) void attn_kernel(
    const unsigned short* __restrict__ qkv, unsigned short* __restrict__ z)
{
  const int n = blockIdx.x, head = blockIdx.y;
  __shared__ float sq[32 * 100];
  __shared__ float sk[32 * 100];
  __shared__ float sv[32 * 100];
  __shared__ float ss[32 * 36];
  const unsigned short* base = qkv + (size_t)n * 32 * 640 + head * 288;
  const int tid = threadIdx.x;

  for (int p = tid; p < 1152; p += 256) {
    int m = p / 384, q = p % 384, r = q / 12, c = (q % 12) * 8;
    ushort8 u = *(const ushort8*)(base + (size_t)r * 640 + m * 96 + c);
    float* dst = (m == 0 ? sq : m == 1 ? sk : sv) + r * 100 + c;
    float4 lo, hi;
    lo.x = bfu2f(u[0]); lo.y = bfu2f(u[1]); lo.z = bfu2f(u[2]); lo.w = bfu2f(u[3]);
    hi.x = bfu2f(u[4]); hi.y = bfu2f(u[5]); hi.z = bfu2f(u[6]); hi.w = bfu2f(u[7]);
    ((float4*)dst)[0] = lo;
    ((float4*)dst)[1] = hi;
  }
  __syncthreads();

  const float scale = 0.1020620726f;  // 1/sqrt(96)
  for (int p = tid; p < 1024; p += 256) {
    int i = p >> 5, j = p & 31;
    float4 a4 = (float4){0.f, 0.f, 0.f, 0.f};
#pragma unroll
    for (int c = 0; c < 96; c += 4) {
      float4 a = *(const float4*)&sq[i * 100 + c];
      float4 b = *(const float4*)&sk[j * 100 + c];
      a4.x += a.x * b.x; a4.y += a.y * b.y; a4.z += a.z * b.z; a4.w += a.w * b.w;
    }
    ss[i * 36 + j] = (a4.x + a4.y + a4.z + a4.w) * scale;
  }
  __syncthreads();

  {
    int r = tid >> 3, g = tid & 7;
    float4 v = *(float4*)&ss[r * 36 + g * 4];
    float mx = fmaxf(fmaxf(v.x, v.y), fmaxf(v.z, v.w));
#pragma unroll
    for (int off = 1; off < 8; off <<= 1) mx = fmaxf(mx, __shfl_xor(mx, off, 64));
    v.x = __expf(v.x - mx); v.y = __expf(v.y - mx);
    v.z = __expf(v.z - mx); v.w = __expf(v.w - mx);
    float sum = v.x + v.y + v.z + v.w;
#pragma unroll
    for (int off = 1; off < 8; off <<= 1) sum += __shfl_xor(sum, off, 64);
    float inv = 1.f / sum;
    v.x *= inv; v.y *= inv; v.z *= inv; v.w *= inv;
    *(float4*)&ss[r * 36 + g * 4] = v;
  }
  __syncthreads();

  for (int p = tid; p < 768; p += 256) {
    int i = p / 24, c = (p % 24) * 4;
    float4 a = (float4){0.f, 0.f, 0.f, 0.f};
#pragma unroll
    for (int j = 0; j < 32; ++j) {
      float w = ss[i * 36 + j];
      float4 vv = *(const float4*)&sv[j * 100 + c];
      a.x += w * vv.x; a.y += w * vv.y; a.z += w * vv.z; a.w += w * vv.w;
    }
    ushort4 u;
    u.x = f2bfu(a.x); u.y = f2bfu(a.y); u.z = f2bfu(a.z); u.w = f2bfu(a.w);
    *(ushort4*)&z[((size_t)n * 32 + i) * 192 + head * 96 + c] = u;
  }
}

// ---------------------------------------------------------------------------
// LayerNorm: bf16 in -> bf16 out. 1 wave per row, 4 rows/block.
// ---------------------------------------------------------------------------
__global__ __launch_bounds__(256) void ln_kernel(
    const unsigned short* __restrict__ t, unsigned short* __restrict__ hb,
    const float* __restrict__ g, const float* __restrict__ b)
{
  const long row = (long)blockIdx.x * 4 + (threadIdx.x >> 6);
  const int lane = threadIdx.x & 63;
  const ushort4* p = (const ushort4*)(t + row * 768);
  float4 v[3];
  float s = 0.f, s2 = 0.f;
#pragma unroll
  for (int j = 0; j < 3; ++j) {
    ushort4 u = p[j * 64 + lane];
    float4 f;
    f.x = bfu2f(u.x); f.y = bfu2f(u.y); f.z = bfu2f(u.z); f.w = bfu2f(u.w);
    v[j] = f;
    s  += f.x + f.y + f.z + f.w;
    s2 += f.x * f.x + f.y * f.y + f.z * f.z + f.w * f.w;
  }
#pragma unroll
  for (int off = 32; off; off >>= 1) {
    s  += __shfl_xor(s, off, 64);
    s2 += __shfl_xor(s2, off, 64);
  }
  const float mean = s * (1.f / 768.f);
  const float var  = s2 * (1.f / 768.f) - mean * mean;
  const float rs   = rsqrtf(var + 1e-5f);
  ushort4* hbo = (ushort4*)(hb + row * 768);
#pragma unroll
  for (int j = 0; j < 3; ++j) {
    int idx = j * 64 + lane;
    float4 gg = ((const float4*)g)[idx];
    float4 bb = ((const float4*)b)[idx];
    ushort4 u;
    u.x = f2bfu((v[j].x - mean) * rs * gg.x + bb.x);
    u.y = f2bfu((v[j].y - mean) * rs * gg.y + bb.y);
    u.z = f2bfu((v[j].z - mean) * rs * gg.z + bb.z);
    u.w = f2bfu((v[j].w - mean) * rs * gg.w + bb.w);
    hbo[idx] = u;
  }
}

// ---------------------------------------------------------------------------
// Final LN + 2-col output projection. bf16 in, f32 out. 1 wave per row.
// ---------------------------------------------------------------------------
__global__ __launch_bounds__(256) void ln_out_kernel(
    const unsigned short* __restrict__ t, const float* __restrict__ g,
    const float* __restrict__ b, const float* __restrict__ Wo,
    const float* __restrict__ bo, float* __restrict__ out)
{
  const long row = (long)blockIdx.x * 4 + (threadIdx.x >> 6);
  const int lane = threadIdx.x & 63;
  const ushort4* p = (const ushort4*)(t + row * 768);
  float4 v[3];
  float s = 0.f, s2 = 0.f;
#pragma unroll
  for (int j = 0; j < 3; ++j) {
    ushort4 u = p[j * 64 + lane];
    float4 f;
    f.x = bfu2f(u.x); f.y = bfu2f(u.y); f.z = bfu2f(u.z); f.w = bfu2f(u.w);
    v[j] = f;
    s  += f.x + f.y + f.z + f.w;
    s2 += f.x * f.x + f.y * f.y + f.z * f.z + f.w * f.w;
  }
#pragma unroll
  for (int off = 32; off; off >>= 1) {
    s  += __shfl_xor(s, off, 64);
    s2 += __shfl_xor(s2, off, 64);
  }
  const float mean = s * (1.f / 768.f);
  const float var  = s2 * (1.f / 768.f) - mean * mean;
  const float rs   = rsqrtf(var + 1e-5f);
  float o0 = 0.f, o1 = 0.f;
#pragma unroll
  for (int j = 0; j < 3; ++j) {
    int idx = j * 64 + lane;
    float4 gg = ((const float4*)g)[idx];
    float4 bb = ((const float4*)b)[idx];
    float4 w0 = ((const float4*)Wo)[idx];
    float4 w1 = ((const float4*)(Wo + 768))[idx];
    float y;
    y = (v[j].x - mean) * rs * gg.x + bb.x; o0 += y * w0.x; o1 += y * w1.x;
    y = (v[j].y - mean) * rs * gg.y + bb.y; o0 += y * w0.y; o1 += y * w1.y;
    y = (v[j].z - mean) * rs * gg.z + bb.z; o0 += y * w0.z; o1 += y * w1.z;
    y = (v[j].w - mean) * rs * gg.w + bb.w; o0 += y * w0.w; o1 += y * w1.w;
  }
#pragma unroll
  for (int off = 32; off; off >>= 1) {
    o0 += __shfl_xor(o0, off, 64);
    o1 += __shfl_xor(o1, off, 64);
  }
  if (lane == 0) {
    out[row * 2 + 0] = o0 + bo[0];
    out[row * 2 + 1] = o1 + bo[1];
  }
}

// sentinel: workspace too small — make it diagnosable (error ~12345)
__global__ void sentinel_kernel(float* out) {
  if (threadIdx.x == 0 && blockIdx.x == 0) out[0] = 12345.0f;
}

// ---------------------------------------------------------------------------
extern "C" void kernel_launch(void* const* d_in, const int* in_sizes, int n_in,
                              void* d_out, int out_size, void* d_ws, size_t ws_size,
                              hipStream_t stream)
{
  const int*   ids = (const int*)  d_in[0];
  const float* emb = (const float*)d_in[1];
  const float* pos = (const float*)d_in[2];
  const float* Wk1 = (const float*)d_in[3];  const float* bk1 = (const float*)d_in[4];
  const float* Wv1 = (const float*)d_in[5];  const float* bv1 = (const float*)d_in[6];
  const float* Wq1 = (const float*)d_in[7];  const float* bq1 = (const float*)d_in[8];
  const float* Wk2 = (const float*)d_in[9];  const float* bk2 = (const float*)d_in[10];
  const float* Wv2 = (const float*)d_in[11]; const float* bv2 = (const float*)d_in[12];
  const float* Wq2 = (const float*)d_in[13]; const float* bq2 = (const float*)d_in[14];
  const float* Wp  = (const float*)d_in[15]; const float* bp  = (const float*)d_in[16];
  const float* g1  = (const float*)d_in[17]; const float* be1 = (const float*)d_in[18];
  const float* W1  = (const float*)d_in[19]; const float* bf1 = (const float*)d_in[20];
  const float* W2  = (const float*)d_in[21]; const float* bf2 = (const float*)d_in[22];
  const float* g2  = (const float*)d_in[23]; const float* be2 = (const float*)d_in[24];
  const float* Wo  = (const float*)d_in[25]; const float* bo  = (const float*)d_in[26];
  float* out = (float*)d_out;

  char* ws = (char*)d_ws;
  size_t off = 0;
  auto alloc = [&](size_t bytes) { void* p = ws + off; off += (bytes + 255) & ~(size_t)255; return p; };

  // weights first (7.3 MiB)
  unsigned short* Wqkv = (unsigned short*)alloc(640 * 768 * 2);
  float*          bqkv = (float*)         alloc(640 * 4);
  unsigned short* Wp_b = (unsigned short*)alloc(768 * 192 * 2);
  unsigned short* W1_b = (unsigned short*)alloc(2048 * 768 * 2);
  unsigned short* W2_b = (unsigned short*)alloc(768 * 2048 * 2);
  const size_t woff = off;

  // adaptive chunking: slabs SA(x->h), SB(qkv->t1->t2), SC(z->f), all bf16
  // C=1 footprint ~904 MiB; halves per step; C=256 (R=512) ~11 MiB.
  long R = NROWS; int C = 1; bool ok = false;
  for (;;) {
    size_t aA = (((size_t)R * 768 * 2) + 255) & ~(size_t)255;
    size_t aC = (((size_t)R * 2048 * 2) + 255) & ~(size_t)255;
    if (woff + 2 * aA + aC <= ws_size) { ok = true; break; }
    if (C == 256) break;
    C <<= 1; R >>= 1;
  }
  if (!ok) {
    sentinel_kernel<<<1, 64, 0, stream>>>(out);
    return;
  }
  const size_t aA = (((size_t)R * 768 * 2) + 255) & ~(size_t)255;
  unsigned short* SA = (unsigned short*)(ws + woff);
  unsigned short* SB = (unsigned short*)(ws + woff + aA);
  unsigned short* SC = (unsigned short*)(ws + woff + 2 * aA);

  // ---- 0. fused weight prep ----
  prep_kernel<<<(3785344 + 255) / 256, 256, 0, stream>>>(
      Wq1, Wk1, Wv1, Wq2, Wk2, Wv2, bq1, bk1, bv1, bq2, bk2, bv2,
      Wp, W1, W2, Wqkv, bqkv, Wp_b, W1_b, W2_b);

  for (int c = 0; c < C; ++c) {
    const long row0 = (long)c * R;
    // 1. embed -> SA (x bf16)
    embed_kernel<<<R / 4, 256, 0, stream>>>(ids + row0, emb, pos, SA);
    // 2. QKV: SB[R,640] = x @ Wqkv^T
    gemm_bt<false, false><<<dim3(5, R / 128), 256, 0, stream>>>(
        SA, Wqkv, bqkv, nullptr, SB, 640, 768);
    // 3. attention -> SC (z bf16 [R,192])
    attn_kernel<<<dim3(R / 32, 2), 256, 0, stream>>>(SB, SC);
    // 4. proj + resid(x): SB[R,768] = z @ Wp^T + bp + x
    gemm_bt<false, true><<<dim3(6, R / 128), 256, 0, stream>>>(
        SC, Wp_b, bp, SA, SB, 768, 192);
    // 5. LN1: SA = LN(SB)
    ln_kernel<<<R / 4, 256, 0, stream>>>(SB, SA, g1, be1);
    // 6. FFN1: SC[R,2048] = relu(h @ W1^T + bf1)
    gemm_bt<true, false><<<dim3(16, R / 128), 256, 0, stream>>>(
        SA, W1_b, bf1, nullptr, SC, 2048, 768);
    // 7. FFN2 + resid(h): SB[R,768] = f @ W2^T + bf2 + h
    gemm_bt<false, true><<<dim3(6, R / 128), 256, 0, stream>>>(
        SC, W2_b, bf2, SA, SB, 768, 2048);
    // 8. LN2 + output projection
    ln_out_kernel<<<R / 4, 256, 0, stream>>>(SB, g2, be2, Wo, bo, out + row0 * 2);
  }
}

// Round 6
// 1726.737 us; speedup vs baseline: 1.3234x; 1.3234x over previous
//
#include <hip/hip_runtime.h>
#include <hip/hip_bf16.h>

typedef __attribute__((ext_vector_type(8))) short short8;
typedef __attribute__((ext_vector_type(8))) unsigned short ushort8;
typedef __attribute__((ext_vector_type(4))) float f32x4;

#define NROWS 131072L   // N*T = 4096*32

__device__ __forceinline__ unsigned short f2bfu(float f) {
  union { float f; unsigned u; } a; a.f = f;
  unsigned r = a.u + 0x7fffu + ((a.u >> 16) & 1u);
  return (unsigned short)(r >> 16);
}
__device__ __forceinline__ float bfu2f(unsigned short u) {
  union { unsigned u; float f; } a; a.u = (unsigned)u << 16; return a.f;
}

__device__ __forceinline__ void llds16(const void* g, void* l) {
  __builtin_amdgcn_global_load_lds(
      (const __attribute__((address_space(1))) void*)g,
      (__attribute__((address_space(3))) void*)l, 16, 0, 0);
}

#define SBAR() asm volatile("s_barrier" ::: "memory")

// ---------------------------------------------------------------------------
// 256x256 8-phase GEMM (T2+T3+T4+T5): C[M,N] = A[M,K] * B[N,K]^T + bias
// 8 waves (2Mx4N), BK=64, half-tile staged dbuf LDS (128 KiB), XOR-swizzled
// ds_read, counted vmcnt(6) once per K-tile, setprio around MFMA clusters.
// Wave (wr,wc): C rows {i*32+wr*16+..}, cols {n*64+wc*16+..} (interleaved so
// qa-half phases read only one A-half / B-half).  Requires M%256==0, N%256==0,
// K%64==0, K>=128.
// ---------------------------------------------------------------------------
template<bool RELU, bool RESID>
__global__ __launch_bounds__(512, 2) void gemm256(
    const unsigned short* __restrict__ A, const unsigned short* __restrict__ B,
    const float* __restrict__ bias, const unsigned short* __restrict__ resid,
    unsigned short* __restrict__ Cb, int N, int K)
{
  __shared__ unsigned short lds[65536];  // A: [dbuf2][half2][8192] ; B: +32768
  const int tid  = threadIdx.x;
  const int lane = tid & 63;
  const int wave = tid >> 6;    // 0..7
  const int wr = wave >> 2;     // 0..1
  const int wc = wave & 3;      // 0..3
  const int KT = K >> 6;

  // XCD-aware bijective swizzle (m204)
  const int gx  = gridDim.x;
  const int nwg = gx * gridDim.y;
  int bid = blockIdx.y * gx + blockIdx.x;
  {
    const int q = nwg >> 3, r = nwg & 7;
    const int xcd = bid & 7, i = bid >> 3;
    bid = (xcd < r ? xcd * (q + 1) : r * (q + 1) + (xcd - r) * q) + i;
  }
  const long brow = (long)(bid / gx) * 256;
  const long bcol = (long)(bid % gx) * 256;

  // ---- staging constants: thread's 2 linear LDS blocks, inverse-swz source
  const int i0  = wave * 128 + lane;        // 16B-block idx (issue 0); issue 1 = i0+64
  const int r0  = i0 >> 3;                  // source row within half (issue 1: r0+8)
  const int js0 = (i0 & 7) ^ (r0 & 7);      // inverse-swizzled 8-elem col chunk (same both issues)

  auto stage = [&](const unsigned short* __restrict__ P, long g0, int s,
                   unsigned short* hb) {
    const int kc = (s < KT ? s : KT - 1) << 6;           // clamp keeps vmcnt counting uniform
    const unsigned short* src = P + (g0 + r0) * (long)K + kc + js0 * 8;
    llds16(src,            hb + i0 * 8);
    llds16(src + 8L * K,   hb + i0 * 8 + 512);
  };

  // ---- reader constants (swizzled ds_read_b128)
  const int wr16r = wr * 16 + (lane & 15);  // A row within half (+mi*32)
  const int wc16r = wc * 16 + (lane & 15);  // B row within half (+nn*64)
  const int ccol  = (lane >> 4) << 4;       // byte col within 64B kk-half
  const int swz   = (lane & 7) << 4;        // XOR bits 4-6

#define READ_A(hp)                                                        \
  _Pragma("unroll") for (int mi = 0; mi < 4; ++mi)                        \
  _Pragma("unroll") for (int kk = 0; kk < 2; ++kk)                        \
    af[mi][kk] = *(const short8*)((hp) + ((((mi*32 + wr16r) * 128) + kk*64 + ccol) ^ swz));

#define READ_B(hp, nb)                                                    \
  _Pragma("unroll") for (int nn = 0; nn < 2; ++nn)                        \
  _Pragma("unroll") for (int kk = 0; kk < 2; ++kk)                        \
    bf[(nb)*2+nn][kk] = *(const short8*)((hp) + ((((nn*64 + wc16r) * 128) + kk*64 + ccol) ^ swz));

#define MFMA_Q(qa, qb)                                                    \
  __builtin_amdgcn_s_setprio(1);                                          \
  _Pragma("unroll") for (int mi = 0; mi < 4; ++mi)                        \
  _Pragma("unroll") for (int nn = 0; nn < 2; ++nn)                        \
  _Pragma("unroll") for (int kk = 0; kk < 2; ++kk)                        \
    acc[(qa)*4+mi][(qb)*2+nn] = __builtin_amdgcn_mfma_f32_16x16x32_bf16(  \
        af[mi][kk], bf[(qb)*2+nn][kk], acc[(qa)*4+mi][(qb)*2+nn], 0,0,0); \
  __builtin_amdgcn_s_setprio(0);

  f32x4 acc[8][4];
#pragma unroll
  for (int i = 0; i < 8; ++i)
#pragma unroll
    for (int n = 0; n < 4; ++n)
      acc[i][n] = (f32x4){0.f, 0.f, 0.f, 0.f};

  // ---- prologue: tile0 (A0,B0,A1,B1) + tile1 (A0,B0,B1); A1(t1) comes in t0/ph1
  stage(A, brow,       0, lds + 0 * 8192);
  stage(B, bcol,       0, lds + 32768 + 0 * 8192);
  stage(A, brow + 128, 0, lds + 1 * 8192);
  stage(B, bcol + 128, 0, lds + 32768 + 1 * 8192);
  stage(A, brow,       1, lds + 2 * 8192);
  stage(B, bcol,       1, lds + 32768 + 2 * 8192);
  stage(B, bcol + 128, 1, lds + 32768 + 3 * 8192);
  asm volatile("s_waitcnt vmcnt(6)" ::: "memory");   // tile0 resident; 3 halves in flight
  SBAR();

  for (int t = 0; t < KT; ++t) {
    const int d  = t & 1;
    const int dn = d ^ 1;
    const char* a0 = (const char*)(lds + (d * 2 + 0) * 8192);
    const char* a1 = (const char*)(lds + (d * 2 + 1) * 8192);
    const char* b0 = (const char*)(lds + 32768 + (d * 2 + 0) * 8192);
    const char* b1 = (const char*)(lds + 32768 + (d * 2 + 1) * 8192);
    short8 af[4][2], bf[4][2];

    // ph1: A-half0 + B-half0 frags ; stage A-half1(t+1) (read by t-1 ph3: done)
    READ_A(a0);
    READ_B(b0, 0);
    stage(A, brow + 128, t + 1, lds + (dn * 2 + 1) * 8192);
    SBAR();
    MFMA_Q(0, 0);
    SBAR();

    // ph2: B-half1 frags ; stage A-half0(t+2) (read in ph1: done)
    READ_B(b1, 1);
    stage(A, brow, t + 2, lds + (d * 2 + 0) * 8192);
    SBAR();
    MFMA_Q(0, 1);
    SBAR();

    // ph3: A-half1 frags ; stage B-half0(t+2) (read in ph1: done)
    READ_A(a1);
    stage(B, bcol, t + 2, lds + 32768 + (d * 2 + 0) * 8192);
    SBAR();
    MFMA_Q(1, 0);
    SBAR();

    // ph4: no reads ; stage B-half1(t+2) (read in ph2: done)
    stage(B, bcol + 128, t + 2, lds + 32768 + (d * 2 + 1) * 8192);
    SBAR();
    MFMA_Q(1, 1);
    // counted vmcnt: forces all 4 halves of t+1 resident; 3 halves (t+2) in flight
    asm volatile("s_waitcnt vmcnt(6)" ::: "memory");
    SBAR();
  }

  // ---- epilogue
  const int fr = lane & 15;
  const int fq = lane >> 4;
#pragma unroll
  for (int i = 0; i < 8; ++i) {
    const long rowb = brow + i * 32 + wr * 16 + fq * 4;
#pragma unroll
    for (int n = 0; n < 4; ++n) {
      const long col = bcol + n * 64 + wc * 16 + fr;
      const float bv = bias[col];
#pragma unroll
      for (int r2 = 0; r2 < 4; ++r2) {
        const long row = rowb + r2;
        float v = acc[i][n][r2] + bv;
        if (RESID) v += bfu2f(resid[row * N + col]);
        if (RELU)  v = fmaxf(v, 0.f);
        Cb[row * N + col] = f2bfu(v);
      }
    }
  }
#undef READ_A
#undef READ_B
#undef MFMA_Q
}

// ---------------------------------------------------------------------------
// 128x128 m97-structure GEMM (kept for proj: K=192). C = A*B^T + bias (+resid)
// ---------------------------------------------------------------------------
template<bool RELU, bool RESID>
__global__ __launch_bounds__(256) void gemm_bt(
    const unsigned short* __restrict__ A, const unsigned short* __restrict__ B,
    const float* __restrict__ bias, const unsigned short* __restrict__ resid,
    unsigned short* __restrict__ Cb, int N, int K)
{
  __shared__ unsigned short lds_a[128 * 64];
  __shared__ unsigned short lds_b[128 * 64];
  const int tid  = threadIdx.x;
  const int lane = tid & 63;
  const int wave = tid >> 6;
  const int wr = wave >> 1, wc = wave & 1;

  const int gx  = gridDim.x;
  const int nwg = gx * gridDim.y;
  int bid = blockIdx.y * gx + blockIdx.x;
  {
    const int q = nwg >> 3, r = nwg & 7;
    const int xcd = bid & 7, i = bid >> 3;
    bid = (xcd < r ? xcd * (q + 1) : r * (q + 1) + (xcd - r) * q) + i;
  }
  const long brow = (long)(bid / gx) * 128;
  const long bcol = (long)(bid % gx) * 128;

  f32x4 acc[4][4];
#pragma unroll
  for (int m = 0; m < 4; ++m)
#pragma unroll
    for (int n = 0; n < 4; ++n)
      acc[m][n] = (f32x4){0.f, 0.f, 0.f, 0.f};

  const int srow = tid >> 3;
  const int scol = (tid & 7) * 8;

  for (int k0 = 0; k0 < K; k0 += 64) {
#pragma unroll
    for (int i = 0; i < 4; ++i) {
      int r = i * 32 + srow;
      llds16(A + (brow + r) * (long)K + k0 + scol, lds_a + r * 64 + scol);
    }
#pragma unroll
    for (int i = 0; i < 4; ++i) {
      int r = i * 32 + srow;
      llds16(B + (bcol + r) * (long)K + k0 + scol, lds_b + r * 64 + scol);
    }
    asm volatile("s_waitcnt vmcnt(0)" ::: "memory");
    __syncthreads();

#pragma unroll
    for (int ks = 0; ks < 2; ++ks) {
      short8 af[4], bfr[4];
#pragma unroll
      for (int m = 0; m < 4; ++m)
        af[m] = *(const short8*)(lds_a + (wr*64 + m*16 + (lane & 15))*64 + ks*32 + (lane >> 4)*8);
#pragma unroll
      for (int n = 0; n < 4; ++n)
        bfr[n] = *(const short8*)(lds_b + (wc*64 + n*16 + (lane & 15))*64 + ks*32 + (lane >> 4)*8);
#pragma unroll
      for (int m = 0; m < 4; ++m)
#pragma unroll
        for (int n = 0; n < 4; ++n)
          acc[m][n] = __builtin_amdgcn_mfma_f32_16x16x32_bf16(af[m], bfr[n], acc[m][n], 0, 0, 0);
    }
    __syncthreads();
  }

  const int fr = lane & 15;
  const int fq = lane >> 4;
#pragma unroll
  for (int m = 0; m < 4; ++m) {
#pragma unroll
    for (int n = 0; n < 4; ++n) {
      long col = bcol + wc*64 + n*16 + fr;
      float bv = bias[col];
#pragma unroll
      for (int r2 = 0; r2 < 4; ++r2) {
        long row = brow + wr*64 + m*16 + fq*4 + r2;
        float v = acc[m][n][r2] + bv;
        if (RESID) v += bfu2f(resid[row * N + col]);
        if (RELU)  v = fmaxf(v, 0.f);
        Cb[row * N + col] = f2bfu(v);
      }
    }
  }
}

// ---------------------------------------------------------------------------
// Fused weight prep. Virtual layout:
// [Wqkv 768*768][bqkv 768][Wp 147456][W1 1572864][W2 1572864] = 3883776
// Wqkv rows: q1 k1 v1 q2 k2 v2 (96 each) + 192 zero rows.
// ---------------------------------------------------------------------------
__global__ __launch_bounds__(256) void prep_kernel(
    const float* __restrict__ Wq1, const float* __restrict__ Wk1, const float* __restrict__ Wv1,
    const float* __restrict__ Wq2, const float* __restrict__ Wk2, const float* __restrict__ Wv2,
    const float* __restrict__ bq1, const float* __restrict__ bk1, const float* __restrict__ bv1,
    const float* __restrict__ bq2, const float* __restrict__ bk2, const float* __restrict__ bv2,
    const float* __restrict__ Wp, const float* __restrict__ W1, const float* __restrict__ W2,
    unsigned short* __restrict__ Wqkv, float* __restrict__ bqkv,
    unsigned short* __restrict__ Wp_b, unsigned short* __restrict__ W1_b,
    unsigned short* __restrict__ W2_b)
{
  long i = (long)blockIdx.x * 256 + threadIdx.x;
  if (i >= 3883776L) return;
  if (i < 589824) {
    int row = (int)(i / 768), col = (int)(i % 768);
    float v = 0.f;
    if (row < 576) {
      int which = row / 96, r = row % 96;
      const float* s = which == 0 ? Wq1 : which == 1 ? Wk1 : which == 2 ? Wv1
                     : which == 3 ? Wq2 : which == 4 ? Wk2 : Wv2;
      v = s[r * 768 + col];
    }
    Wqkv[i] = f2bfu(v);
    return;
  }
  i -= 589824;
  if (i < 768) {
    float v = 0.f;
    if (i < 576) {
      int which = (int)(i / 96), r = (int)(i % 96);
      const float* s = which == 0 ? bq1 : which == 1 ? bk1 : which == 2 ? bv1
                     : which == 3 ? bq2 : which == 4 ? bk2 : bv2;
      v = s[r];
    }
    bqkv[i] = v;
    return;
  }
  i -= 768;
  if (i < 147456) { Wp_b[i] = f2bfu(Wp[i]); return; }
  i -= 147456;
  if (i < 1572864) { W1_b[i] = f2bfu(W1[i]); return; }
  i -= 1572864;
  W2_b[i] = f2bfu(W2[i]);
}

// ---------------------------------------------------------------------------
// embed: xb = bf16(emb[ids] + pos). 4 rows/block, 1 wave/row.
// ---------------------------------------------------------------------------
__global__ __launch_bounds__(256) void embed_kernel(
    const int* __restrict__ ids, const float* __restrict__ emb,
    const float* __restrict__ pos, unsigned short* __restrict__ xb)
{
  const long row  = (long)blockIdx.x * 4 + (threadIdx.x >> 6);
  const int lane = threadIdx.x & 63;
  const int tok  = ids[row];
  const int tp   = (int)(row & 31);
  const float4* e = (const float4*)(emb + (size_t)tok * 768);
  const float4* p = (const float4*)(pos + (size_t)tp * 768);
  ushort4* bo = (ushort4*)(xb + row * 768);
#pragma unroll
  for (int j = 0; j < 3; ++j) {
    int idx = j * 64 + lane;
    float4 v = e[idx];
    float4 q = p[idx];
    v.x += q.x; v.y += q.y; v.z += q.z; v.w += q.w;
    ushort4 u;
    u.x = f2bfu(v.x); u.y = f2bfu(v.y); u.z = f2bfu(v.z); u.w = f2bfu(v.w);
    bo[idx] = u;
  }
}

// ---------------------------------------------------------------------------
// attention: one block per (seq, head). qkv bf16 [rows][768],
// row cols: [q1 k1 v1 q2 k2 v2 pad] each 96.  z out bf16 [rows][192].
// ---------------------------------------------------------------------------
__global__ __launch_bounds__(256) void attn_kernel(
    const unsigned short* __restrict__ qkv, unsigned short* __restrict__ z)
{
  const int n = blockIdx.x, head = blockIdx.y;
  __shared__ float sq[32 * 100];
  __shared__ float sk[32 * 100];
  __shared__ float sv[32 * 100];
  __shared__ float ss[32 * 36];
  const unsigned short* base = qkv + (size_t)n * 32 * 768 + head * 288;
  const int tid = threadIdx.x;

  for (int p = tid; p < 1152; p += 256) {
    int m = p / 384, q = p % 384, r = q / 12, c = (q % 12) * 8;
    ushort8 u = *(const ushort8*)(base + (size_t)r * 768 + m * 96 + c);
    float* dst = (m == 0 ? sq : m == 1 ? sk : sv) + r * 100 + c;
    float4 lo, hi;
    lo.x = bfu2f(u[0]); lo.y = bfu2f(u[1]); lo.z = bfu2f(u[2]); lo.w = bfu2f(u[3]);
    hi.x = bfu2f(u[4]); hi.y = bfu2f(u[5]); hi.z = bfu2f(u[6]); hi.w = bfu2f(u[7]);
    ((float4*)dst)[0] = lo;
    ((float4*)dst)[1] = hi;
  }
  __syncthreads();

  const float scale = 0.1020620726f;  // 1/sqrt(96)
  for (int p = tid; p < 1024; p += 256) {
    int i = p >> 5, j = p & 31;
    float4 a4 = (float4){0.f, 0.f, 0.f, 0.f};
#pragma unroll
    for (int c = 0; c < 96; c += 4) {
      float4 a = *(const float4*)&sq[i * 100 + c];
      float4 b = *(const float4*)&sk[j * 100 + c];
      a4.x += a.x * b.x; a4.y += a.y * b.y; a4.z += a.z * b.z; a4.w += a.w * b.w;
    }
    ss[i * 36 + j] = (a4.x + a4.y + a4.z + a4.w) * scale;
  }
  __syncthreads();

  {
    int r = tid >> 3, g = tid & 7;
    float4 v = *(float4*)&ss[r * 36 + g * 4];
    float mx = fmaxf(fmaxf(v.x, v.y), fmaxf(v.z, v.w));
#pragma unroll
    for (int off = 1; off < 8; off <<= 1) mx = fmaxf(mx, __shfl_xor(mx, off, 64));
    v.x = __expf(v.x - mx); v.y = __expf(v.y - mx);
    v.z = __expf(v.z - mx); v.w = __expf(v.w - mx);
    float sum = v.x + v.y + v.z + v.w;
#pragma unroll
    for (int off = 1; off < 8; off <<= 1) sum += __shfl_xor(sum, off, 64);
    float inv = 1.f / sum;
    v.x *= inv; v.y *= inv; v.z *= inv; v.w *= inv;
    *(float4*)&ss[r * 36 + g * 4] = v;
  }
  __syncthreads();

  for (int p = tid; p < 768; p += 256) {
    int i = p / 24, c = (p % 24) * 4;
    float4 a = (float4){0.f, 0.f, 0.f, 0.f};
#pragma unroll
    for (int j = 0; j < 32; ++j) {
      float w = ss[i * 36 + j];
      float4 vv = *(const float4*)&sv[j * 100 + c];
      a.x += w * vv.x; a.y += w * vv.y; a.z += w * vv.z; a.w += w * vv.w;
    }
    ushort4 u;
    u.x = f2bfu(a.x); u.y = f2bfu(a.y); u.z = f2bfu(a.z); u.w = f2bfu(a.w);
    *(ushort4*)&z[((size_t)n * 32 + i) * 192 + head * 96 + c] = u;
  }
}

// ---------------------------------------------------------------------------
// LayerNorm: bf16 in -> bf16 out. 1 wave per row, 4 rows/block.
// ---------------------------------------------------------------------------
__global__ __launch_bounds__(256) void ln_kernel(
    const unsigned short* __restrict__ t, unsigned short* __restrict__ hb,
    const float* __restrict__ g, const float* __restrict__ b)
{
  const long row = (long)blockIdx.x * 4 + (threadIdx.x >> 6);
  const int lane = threadIdx.x & 63;
  const ushort4* p = (const ushort4*)(t + row * 768);
  float4 v[3];
  float s = 0.f, s2 = 0.f;
#pragma unroll
  for (int j = 0; j < 3; ++j) {
    ushort4 u = p[j * 64 + lane];
    float4 f;
    f.x = bfu2f(u.x); f.y = bfu2f(u.y); f.z = bfu2f(u.z); f.w = bfu2f(u.w);
    v[j] = f;
    s  += f.x + f.y + f.z + f.w;
    s2 += f.x * f.x + f.y * f.y + f.z * f.z + f.w * f.w;
  }
#pragma unroll
  for (int off = 32; off; off >>= 1) {
    s  += __shfl_xor(s, off, 64);
    s2 += __shfl_xor(s2, off, 64);
  }
  const float mean = s * (1.f / 768.f);
  const float var  = s2 * (1.f / 768.f) - mean * mean;
  const float rs   = rsqrtf(var + 1e-5f);
  ushort4* hbo = (ushort4*)(hb + row * 768);
#pragma unroll
  for (int j = 0; j < 3; ++j) {
    int idx = j * 64 + lane;
    float4 gg = ((const float4*)g)[idx];
    float4 bb = ((const float4*)b)[idx];
    ushort4 u;
    u.x = f2bfu((v[j].x - mean) * rs * gg.x + bb.x);
    u.y = f2bfu((v[j].y - mean) * rs * gg.y + bb.y);
    u.z = f2bfu((v[j].z - mean) * rs * gg.z + bb.z);
    u.w = f2bfu((v[j].w - mean) * rs * gg.w + bb.w);
    hbo[idx] = u;
  }
}

// ---------------------------------------------------------------------------
// Final LN + 2-col output projection. bf16 in, f32 out. 1 wave per row.
// ---------------------------------------------------------------------------
__global__ __launch_bounds__(256) void ln_out_kernel(
    const unsigned short* __restrict__ t, const float* __restrict__ g,
    const float* __restrict__ b, const float* __restrict__ Wo,
    const float* __restrict__ bo, float* __restrict__ out)
{
  const long row = (long)blockIdx.x * 4 + (threadIdx.x >> 6);
  const int lane = threadIdx.x & 63;
  const ushort4* p = (const ushort4*)(t + row * 768);
  float4 v[3];
  float s = 0.f, s2 = 0.f;
#pragma unroll
  for (int j = 0; j < 3; ++j) {
    ushort4 u = p[j * 64 + lane];
    float4 f;
    f.x = bfu2f(u.x); f.y = bfu2f(u.y); f.z = bfu2f(u.z); f.w = bfu2f(u.w);
    v[j] = f;
    s  += f.x + f.y + f.z + f.w;
    s2 += f.x * f.x + f.y * f.y + f.z * f.z + f.w * f.w;
  }
#pragma unroll
  for (int off = 32; off; off >>= 1) {
    s  += __shfl_xor(s, off, 64);
    s2 += __shfl_xor(s2, off, 64);
  }
  const float mean = s * (1.f / 768.f);
  const float var  = s2 * (1.f / 768.f) - mean * mean;
  const float rs   = rsqrtf(var + 1e-5f);
  float o0 = 0.f, o1 = 0.f;
#pragma unroll
  for (int j = 0; j < 3; ++j) {
    int idx = j * 64 + lane;
    float4 gg = ((const float4*)g)[idx];
    float4 bb = ((const float4*)b)[idx];
    float4 w0 = ((const float4*)Wo)[idx];
    float4 w1 = ((const float4*)(Wo + 768))[idx];
    float y;
    y = (v[j].x - mean) * rs * gg.x + bb.x; o0 += y * w0.x; o1 += y * w1.x;
    y = (v[j].y - mean) * rs * gg.y + bb.y; o0 += y * w0.y; o1 += y * w1.y;
    y = (v[j].z - mean) * rs * gg.z + bb.z; o0 += y * w0.z; o1 += y * w1.z;
    y = (v[j].w - mean) * rs * gg.w + bb.w; o0 += y * w0.w; o1 += y * w1.w;
  }
#pragma unroll
  for (int off = 32; off; off >>= 1) {
    o0 += __shfl_xor(o0, off, 64);
    o1 += __shfl_xor(o1, off, 64);
  }
  if (lane == 0) {
    out[row * 2 + 0] = o0 + bo[0];
    out[row * 2 + 1] = o1 + bo[1];
  }
}

// sentinel: workspace too small — diagnosable (error ~12345)
__global__ void sentinel_kernel(float* out) {
  if (threadIdx.x == 0 && blockIdx.x == 0) out[0] = 12345.0f;
}

// ---------------------------------------------------------------------------
extern "C" void kernel_launch(void* const* d_in, const int* in_sizes, int n_in,
                              void* d_out, int out_size, void* d_ws, size_t ws_size,
                              hipStream_t stream)
{
  const int*   ids = (const int*)  d_in[0];
  const float* emb = (const float*)d_in[1];
  const float* pos = (const float*)d_in[2];
  const float* Wk1 = (const float*)d_in[3];  const float* bk1 = (const float*)d_in[4];
  const float* Wv1 = (const float*)d_in[5];  const float* bv1 = (const float*)d_in[6];
  const float* Wq1 = (const float*)d_in[7];  const float* bq1 = (const float*)d_in[8];
  const float* Wk2 = (const float*)d_in[9];  const float* bk2 = (const float*)d_in[10];
  const float* Wv2 = (const float*)d_in[11]; const float* bv2 = (const float*)d_in[12];
  const float* Wq2 = (const float*)d_in[13]; const float* bq2 = (const float*)d_in[14];
  const float* Wp  = (const float*)d_in[15]; const float* bp  = (const float*)d_in[16];
  const float* g1  = (const float*)d_in[17]; const float* be1 = (const float*)d_in[18];
  const float* W1  = (const float*)d_in[19]; const float* bf1 = (const float*)d_in[20];
  const float* W2  = (const float*)d_in[21]; const float* bf2 = (const float*)d_in[22];
  const float* g2  = (const float*)d_in[23]; const float* be2 = (const float*)d_in[24];
  const float* Wo  = (const float*)d_in[25]; const float* bo  = (const float*)d_in[26];
  float* out = (float*)d_out;

  char* ws = (char*)d_ws;
  size_t off = 0;
  auto alloc = [&](size_t bytes) { void* p = ws + off; off += (bytes + 255) & ~(size_t)255; return p; };

  // weights (bf16) ~7.5 MiB
  unsigned short* Wqkv = (unsigned short*)alloc(768 * 768 * 2);
  float*          bqkv = (float*)         alloc(768 * 4);
  unsigned short* Wp_b = (unsigned short*)alloc(768 * 192 * 2);
  unsigned short* W1_b = (unsigned short*)alloc(2048 * 768 * 2);
  unsigned short* W2_b = (unsigned short*)alloc(768 * 2048 * 2);
  const size_t woff = off;

  // adaptive chunking: slabs SA(x->h), SB(qkv->t1->t2), SC(z->f), all bf16
  long R = NROWS; int C = 1; bool ok = false;
  for (;;) {
    size_t aA = (((size_t)R * 768 * 2) + 255) & ~(size_t)255;
    size_t aC = (((size_t)R * 2048 * 2) + 255) & ~(size_t)255;
    if (woff + 2 * aA + aC <= ws_size) { ok = true; break; }
    if (C == 256) break;
    C <<= 1; R >>= 1;
  }
  if (!ok) {
    sentinel_kernel<<<1, 64, 0, stream>>>(out);
    return;
  }
  const size_t aA = (((size_t)R * 768 * 2) + 255) & ~(size_t)255;
  unsigned short* SA = (unsigned short*)(ws + woff);
  unsigned short* SB = (unsigned short*)(ws + woff + aA);
  unsigned short* SC = (unsigned short*)(ws + woff + 2 * aA);

  // ---- 0. fused weight prep ----
  prep_kernel<<<(3883776 + 255) / 256, 256, 0, stream>>>(
      Wq1, Wk1, Wv1, Wq2, Wk2, Wv2, bq1, bk1, bv1, bq2, bk2, bv2,
      Wp, W1, W2, Wqkv, bqkv, Wp_b, W1_b, W2_b);

  for (int c = 0; c < C; ++c) {
    const long row0 = (long)c * R;
    // 1. embed -> SA (x bf16)
    embed_kernel<<<R / 4, 256, 0, stream>>>(ids + row0, emb, pos, SA);
    // 2. QKV (padded N=768): SB[R,768] = x @ Wqkv^T
    gemm256<false, false><<<dim3(3, R / 256), 512, 0, stream>>>(
        SA, Wqkv, bqkv, nullptr, SB, 768, 768);
    // 3. attention -> SC (z bf16 [R,192])
    attn_kernel<<<dim3(R / 32, 2), 256, 0, stream>>>(SB, SC);
    // 4. proj + resid(x): SB[R,768] = z @ Wp^T + bp + x   (K=192 -> 128^2 kernel)
    gemm_bt<false, true><<<dim3(6, R / 128), 256, 0, stream>>>(
        SC, Wp_b, bp, SA, SB, 768, 192);
    // 5. LN1: SA = LN(SB)
    ln_kernel<<<R / 4, 256, 0, stream>>>(SB, SA, g1, be1);
    // 6. FFN1: SC[R,2048] = relu(h @ W1^T + bf1)
    gemm256<true, false><<<dim3(8, R / 256), 512, 0, stream>>>(
        SA, W1_b, bf1, nullptr, SC, 2048, 768);
    // 7. FFN2 + resid(h): SB[R,768] = f @ W2^T + bf2 + h
    gemm256<false, true><<<dim3(3, R / 256), 512, 0, stream>>>(
        SC, W2_b, bf2, SA, SB, 768, 2048);
    // 8. LN2 + output projection
    ln_out_kernel<<<R / 4, 256, 0, stream>>>(SB, g2, be2, Wo, bo, out + row0 * 2);
  }
}

// Round 8
// 1700.790 us; speedup vs baseline: 1.3436x; 1.0153x over previous
//
#include <hip/hip_runtime.h>
#include <hip/hip_bf16.h>

typedef __attribute__((ext_vector_type(8))) short short8;
typedef __attribute__((ext_vector_type(8))) unsigned short ushort8;
typedef __attribute__((ext_vector_type(4))) float f32x4;

#define NROWS 131072L   // N*T = 4096*32

__device__ __forceinline__ unsigned short f2bfu(float f) {
  union { float f; unsigned u; } a; a.f = f;
  unsigned r = a.u + 0x7fffu + ((a.u >> 16) & 1u);
  return (unsigned short)(r >> 16);
}
__device__ __forceinline__ float bfu2f(unsigned short u) {
  union { unsigned u; float f; } a; a.u = (unsigned)u << 16; return a.f;
}

__device__ __forceinline__ void llds16(const void* g, void* l) {
  __builtin_amdgcn_global_load_lds(
      (const __attribute__((address_space(1))) void*)g,
      (__attribute__((address_space(3))) void*)l, 16, 0, 0);
}

#define SBAR() asm volatile("s_barrier" ::: "memory")

// ---------------------------------------------------------------------------
// 256x256 8-phase GEMM (T2+T3+T4+T5): C[M,N] = A[M,K] * B[N,K]^T + bias
// 8 waves (2Mx4N), BK=64, half-tile staged dbuf LDS (128 KiB), XOR-swizzled
// ds_read, counted vmcnt(6) once per K-tile, setprio around MFMA clusters.
// R7: address arithmetic hoisted — XOR split into per-thread base pointers +
// compile-time offsets; K-loop unrolled x2 so dbuf parity is a literal.
// Requires M%256==0, N%256==0, K%128==0 (KT even), K>=128.
// ---------------------------------------------------------------------------
template<bool RELU, bool RESID>
__global__ __launch_bounds__(512, 2) void gemm256(
    const unsigned short* __restrict__ A, const unsigned short* __restrict__ B,
    const float* __restrict__ bias, const unsigned short* __restrict__ resid,
    unsigned short* __restrict__ Cb, int N, int K)
{
  __shared__ unsigned short lds[65536];  // A: bytes [0,65536) ; B: [65536,131072)
  const int tid  = threadIdx.x;
  const int lane = tid & 63;
  const int wave = tid >> 6;    // 0..7
  const int wr = wave >> 2;     // 0..1
  const int wc = wave & 3;      // 0..3
  const int KT = K >> 6;

  // XCD-aware bijective swizzle (m204)
  const int gx  = gridDim.x;
  const int nwg = gx * gridDim.y;
  int bid = blockIdx.y * gx + blockIdx.x;
  {
    const int q = nwg >> 3, r = nwg & 7;
    const int xcd = bid & 7, i = bid >> 3;
    bid = (xcd < r ? xcd * (q + 1) : r * (q + 1) + (xcd - r) * q) + i;
  }
  const long brow = (long)(bid / gx) * 256;
  const long bcol = (long)(bid % gx) * 256;

  // ---- staging: thread's 2 linear LDS 16B-blocks, inverse-swizzled source
  const int i0  = wave * 128 + lane;        // 16B-block idx (issue 0); issue 1 = +64
  const int r0  = i0 >> 3;                  // source row within half (issue 1: +8)
  const int js0 = (i0 & 7) ^ (r0 & 7);      // inverse-swizzled 8-elem col chunk
  const int i0x16 = i0 * 16;                // LDS byte offset of issue-0 block
  char* Lb = (char*)lds;

  // precomputed global source bases (half0/half1 of A and B)
  const char* sA0 = (const char*)(A + (brow + r0) * (long)K + js0 * 8);
  const char* sA1 = sA0 + 256L * K;         // +128 rows (bytes)
  const char* sB0 = (const char*)(B + (bcol + r0) * (long)K + js0 * 8);
  const char* sB1 = sB0 + 256L * K;
  const long d8K = 16L * K;                 // issue-1 source delta (+8 rows, bytes)

  auto stage = [&](const char* srcBase, int s, int ldsByteOff) {
    const int kb = (s < KT ? s : KT - 1) << 7;   // K-tile byte offset (clamped)
    const char* p = srcBase + kb;
    char* dst = Lb + ldsByteOff + i0x16;
    llds16(p,       dst);
    llds16(p + d8K, dst + 1024);
  };

  // ---- reader base pointers: XOR pre-applied, loop-invariant
  const int wr16r = wr * 16 + (lane & 15);  // A row within half (+mi*32)
  const int wc16r = wc * 16 + (lane & 15);  // B row within half (+nn*64)
  const int ccol  = (lane >> 4) << 4;       // byte col within 64B kk-half
  const int swz   = (lane & 7) << 4;        // XOR bits 4-6
  const int kx0 = (0  + ccol) ^ swz;        // kk=0 within-row byte (swizzled)
  const int kx1 = (64 + ccol) ^ swz;        // kk=1
  const char* pA0 = (const char*)lds + wr16r * 128 + kx0;
  const char* pA1 = (const char*)lds + wr16r * 128 + kx1;
  const char* pB0 = (const char*)lds + 65536 + wc16r * 128 + kx0;
  const char* pB1 = (const char*)lds + 65536 + wc16r * 128 + kx1;

#define RDA(D, H)                                                            \
  _Pragma("unroll") for (int mi = 0; mi < 4; ++mi) {                         \
    af[mi][0] = *(const short8*)(pA0 + (((D)*2+(H)) * 16384 + mi * 4096));   \
    af[mi][1] = *(const short8*)(pA1 + (((D)*2+(H)) * 16384 + mi * 4096));   \
  }
#define RDB(D, H, NB)                                                        \
  _Pragma("unroll") for (int nn = 0; nn < 2; ++nn) {                         \
    bf[(NB)*2+nn][0] = *(const short8*)(pB0 + (((D)*2+(H)) * 16384 + nn * 8192)); \
    bf[(NB)*2+nn][1] = *(const short8*)(pB1 + (((D)*2+(H)) * 16384 + nn * 8192)); \
  }
#define MFMA_Q(qa, qb)                                                       \
  __builtin_amdgcn_s_setprio(1);                                             \
  _Pragma("unroll") for (int mi = 0; mi < 4; ++mi)                           \
  _Pragma("unroll") for (int nn = 0; nn < 2; ++nn)                           \
  _Pragma("unroll") for (int kk = 0; kk < 2; ++kk)                           \
    acc[(qa)*4+mi][(qb)*2+nn] = __builtin_amdgcn_mfma_f32_16x16x32_bf16(     \
        af[mi][kk], bf[(qb)*2+nn][kk], acc[(qa)*4+mi][(qb)*2+nn], 0,0,0);    \
  __builtin_amdgcn_s_setprio(0);

// one K-tile, dbuf parity D as literal; stage targets per original schedule
#define KTILE(D, T)                                                          \
  {                                                                          \
    short8 af[4][2], bf[4][2];                                               \
    /* ph1: read A0,B0 ; stage A-half1(t+1) into other dbuf */               \
    RDA(D, 0)                                                                \
    RDB(D, 0, 0)                                                             \
    stage(sA1, (T) + 1, (((D)^1) * 2 + 1) * 16384);                          \
    asm volatile("s_waitcnt lgkmcnt(8)" ::: "memory");                       \
    SBAR();                                                                  \
    MFMA_Q(0, 0)                                                             \
    SBAR();                                                                  \
    /* ph2: read B1 ; stage A-half0(t+2) (this dbuf, read done in ph1) */    \
    RDB(D, 1, 1)                                                             \
    stage(sA0, (T) + 2, ((D) * 2 + 0) * 16384);                              \
    SBAR();                                                                  \
    MFMA_Q(0, 1)                                                             \
    SBAR();                                                                  \
    /* ph3: read A1 ; stage B-half0(t+2) */                                  \
    RDA(D, 1)                                                                \
    stage(sB0, (T) + 2, 65536 + ((D) * 2 + 0) * 16384);                      \
    SBAR();                                                                  \
    MFMA_Q(1, 0)                                                             \
    SBAR();                                                                  \
    /* ph4: stage B-half1(t+2) */                                            \
    stage(sB1, (T) + 2, 65536 + ((D) * 2 + 1) * 16384);                      \
    SBAR();                                                                  \
    MFMA_Q(1, 1)                                                             \
    asm volatile("s_waitcnt vmcnt(6)" ::: "memory");                         \
    SBAR();                                                                  \
  }

  f32x4 acc[8][4];
#pragma unroll
  for (int i = 0; i < 8; ++i)
#pragma unroll
    for (int n = 0; n < 4; ++n)
      acc[i][n] = (f32x4){0.f, 0.f, 0.f, 0.f};

  // ---- prologue: tile0 (A0,B0,A1,B1) + tile1 (A0,B0,B1); A1(t1) in t0/ph1
  stage(sA0, 0, 0 * 16384);
  stage(sB0, 0, 65536 + 0 * 16384);
  stage(sA1, 0, 1 * 16384);
  stage(sB1, 0, 65536 + 1 * 16384);
  stage(sA0, 1, 2 * 16384);
  stage(sB0, 1, 65536 + 2 * 16384);
  stage(sB1, 1, 65536 + 3 * 16384);
  asm volatile("s_waitcnt vmcnt(6)" ::: "memory");   // tile0 resident
  SBAR();

  for (int t = 0; t < KT; t += 2) {
    KTILE(0, t)
    KTILE(1, t + 1)
  }

  // ---- epilogue
  const int fr = lane & 15;
  const int fq = lane >> 4;
#pragma unroll
  for (int i = 0; i < 8; ++i) {
    const long rowb = brow + i * 32 + wr * 16 + fq * 4;
#pragma unroll
    for (int n = 0; n < 4; ++n) {
      const long col = bcol + n * 64 + wc * 16 + fr;
      const float bv = bias[col];
#pragma unroll
      for (int r2 = 0; r2 < 4; ++r2) {
        const long row = rowb + r2;
        float v = acc[i][n][r2] + bv;
        if (RESID) v += bfu2f(resid[row * N + col]);
        if (RELU)  v = fmaxf(v, 0.f);
        Cb[row * N + col] = f2bfu(v);
      }
    }
  }
#undef RDA
#undef RDB
#undef MFMA_Q
#undef KTILE
}

// ---------------------------------------------------------------------------
// 128x128 m97-structure GEMM (kept for proj: K=192). C = A*B^T + bias (+resid)
// ---------------------------------------------------------------------------
template<bool RELU, bool RESID>
__global__ __launch_bounds__(256) void gemm_bt(
    const unsigned short* __restrict__ A, const unsigned short* __restrict__ B,
    const float* __restrict__ bias, const unsigned short* __restrict__ resid,
    unsigned short* __restrict__ Cb, int N, int K)
{
  __shared__ unsigned short lds_a[128 * 64];
  __shared__ unsigned short lds_b[128 * 64];
  const int tid  = threadIdx.x;
  const int lane = tid & 63;
  const int wave = tid >> 6;
  const int wr = wave >> 1, wc = wave & 1;

  const int gx  = gridDim.x;
  const int nwg = gx * gridDim.y;
  int bid = blockIdx.y * gx + blockIdx.x;
  {
    const int q = nwg >> 3, r = nwg & 7;
    const int xcd = bid & 7, i = bid >> 3;
    bid = (xcd < r ? xcd * (q + 1) : r * (q + 1) + (xcd - r) * q) + i;
  }
  const long brow = (long)(bid / gx) * 128;
  const long bcol = (long)(bid % gx) * 128;

  f32x4 acc[4][4];
#pragma unroll
  for (int m = 0; m < 4; ++m)
#pragma unroll
    for (int n = 0; n < 4; ++n)
      acc[m][n] = (f32x4){0.f, 0.f, 0.f, 0.f};

  const int srow = tid >> 3;
  const int scol = (tid & 7) * 8;

  for (int k0 = 0; k0 < K; k0 += 64) {
#pragma unroll
    for (int i = 0; i < 4; ++i) {
      int r = i * 32 + srow;
      llds16(A + (brow + r) * (long)K + k0 + scol, lds_a + r * 64 + scol);
    }
#pragma unroll
    for (int i = 0; i < 4; ++i) {
      int r = i * 32 + srow;
      llds16(B + (bcol + r) * (long)K + k0 + scol, lds_b + r * 64 + scol);
    }
    asm volatile("s_waitcnt vmcnt(0)" ::: "memory");
    __syncthreads();

#pragma unroll
    for (int ks = 0; ks < 2; ++ks) {
      short8 af[4], bfr[4];
#pragma unroll
      for (int m = 0; m < 4; ++m)
        af[m] = *(const short8*)(lds_a + (wr*64 + m*16 + (lane & 15))*64 + ks*32 + (lane >> 4)*8);
#pragma unroll
      for (int n = 0; n < 4; ++n)
        bfr[n] = *(const short8*)(lds_b + (wc*64 + n*16 + (lane & 15))*64 + ks*32 + (lane >> 4)*8);
#pragma unroll
      for (int m = 0; m < 4; ++m)
#pragma unroll
        for (int n = 0; n < 4; ++n)
          acc[m][n] = __builtin_amdgcn_mfma_f32_16x16x32_bf16(af[m], bfr[n], acc[m][n], 0, 0, 0);
    }
    __syncthreads();
  }

  const int fr = lane & 15;
  const int fq = lane >> 4;
#pragma unroll
  for (int m = 0; m < 4; ++m) {
#pragma unroll
    for (int n = 0; n < 4; ++n) {
      long col = bcol + wc*64 + n*16 + fr;
      float bv = bias[col];
#pragma unroll
      for (int r2 = 0; r2 < 4; ++r2) {
        long row = brow + wr*64 + m*16 + fq*4 + r2;
        float v = acc[m][n][r2] + bv;
        if (RESID) v += bfu2f(resid[row * N + col]);
        if (RELU)  v = fmaxf(v, 0.f);
        Cb[row * N + col] = f2bfu(v);
      }
    }
  }
}

// ---------------------------------------------------------------------------
// Fused weight prep. Virtual layout:
// [Wqkv 768*768][bqkv 768][Wp 147456][W1 1572864][W2 1572864] = 3883776
// Wqkv rows: q1 k1 v1 q2 k2 v2 (96 each) + 192 zero rows.
// ---------------------------------------------------------------------------
__global__ __launch_bounds__(256) void prep_kernel(
    const float* __restrict__ Wq1, const float* __restrict__ Wk1, const float* __restrict__ Wv1,
    const float* __restrict__ Wq2, const float* __restrict__ Wk2, const float* __restrict__ Wv2,
    const float* __restrict__ bq1, const float* __restrict__ bk1, const float* __restrict__ bv1,
    const float* __restrict__ bq2, const float* __restrict__ bk2, const float* __restrict__ bv2,
    const float* __restrict__ Wp, const float* __restrict__ W1, const float* __restrict__ W2,
    unsigned short* __restrict__ Wqkv, float* __restrict__ bqkv,
    unsigned short* __restrict__ Wp_b, unsigned short* __restrict__ W1_b,
    unsigned short* __restrict__ W2_b)
{
  long i = (long)blockIdx.x * 256 + threadIdx.x;
  if (i >= 3883776L) return;
  if (i < 589824) {
    int row = (int)(i / 768), col = (int)(i % 768);
    float v = 0.f;
    if (row < 576) {
      int which = row / 96, r = row % 96;
      const float* s = which == 0 ? Wq1 : which == 1 ? Wk1 : which == 2 ? Wv1
                     : which == 3 ? Wq2 : which == 4 ? Wk2 : Wv2;
      v = s[r * 768 + col];
    }
    Wqkv[i] = f2bfu(v);
    return;
  }
  i -= 589824;
  if (i < 768) {
    float v = 0.f;
    if (i < 576) {
      int which = (int)(i / 96), r = (int)(i % 96);
      const float* s = which == 0 ? bq1 : which == 1 ? bk1 : which == 2 ? bv1
                     : which == 3 ? bq2 : which == 4 ? bk2 : bv2;
      v = s[r];
    }
    bqkv[i] = v;
    return;
  }
  i -= 768;
  if (i < 147456) { Wp_b[i] = f2bfu(Wp[i]); return; }
  i -= 147456;
  if (i < 1572864) { W1_b[i] = f2bfu(W1[i]); return; }
  i -= 1572864;
  W2_b[i] = f2bfu(W2[i]);
}

// ---------------------------------------------------------------------------
// embed: xb = bf16(emb[ids] + pos). 4 rows/block, 1 wave/row.
// ---------------------------------------------------------------------------
__global__ __launch_bounds__(256) void embed_kernel(
    const int* __restrict__ ids, const float* __restrict__ emb,
    const float* __restrict__ pos, unsigned short* __restrict__ xb)
{
  const long row  = (long)blockIdx.x * 4 + (threadIdx.x >> 6);
  const int lane = threadIdx.x & 63;
  const int tok  = ids[row];
  const int tp   = (int)(row & 31);
  const float4* e = (const float4*)(emb + (size_t)tok * 768);
  const float4* p = (const float4*)(pos + (size_t)tp * 768);
  ushort4* bo = (ushort4*)(xb + row * 768);
#pragma unroll
  for (int j = 0; j < 3; ++j) {
    int idx = j * 64 + lane;
    float4 v = e[idx];
    float4 q = p[idx];
    v.x += q.x; v.y += q.y; v.z += q.z; v.w += q.w;
    ushort4 u;
    u.x = f2bfu(v.x); u.y = f2bfu(v.y); u.z = f2bfu(v.z); u.w = f2bfu(v.w);
    bo[idx] = u;
  }
}

// ---------------------------------------------------------------------------
// attention: one block per (seq, head). qkv bf16 [rows][768],
// row cols: [q1 k1 v1 q2 k2 v2 pad] each 96.  z out bf16 [rows][192].
// ---------------------------------------------------------------------------
__global__ __launch_bounds__(256) void attn_kernel(
    const unsigned short* __restrict__ qkv, unsigned short* __restrict__ z)
{
  const int n = blockIdx.x, head = blockIdx.y;
  __shared__ float sq[32 * 100];
  __shared__ float sk[32 * 100];
  __shared__ float sv[32 * 100];
  __shared__ float ss[32 * 36];
  const unsigned short* base = qkv + (size_t)n * 32 * 768 + head * 288;
  const int tid = threadIdx.x;

  for (int p = tid; p < 1152; p += 256) {
    int m = p / 384, q = p % 384, r = q / 12, c = (q % 12) * 8;
    ushort8 u = *(const ushort8*)(base + (size_t)r * 768 + m * 96 + c);
    float* dst = (m == 0 ? sq : m == 1 ? sk : sv) + r * 100 + c;
    float4 lo, hi;
    lo.x = bfu2f(u[0]); lo.y = bfu2f(u[1]); lo.z = bfu2f(u[2]); lo.w = bfu2f(u[3]);
    hi.x = bfu2f(u[4]); hi.y = bfu2f(u[5]); hi.z = bfu2f(u[6]); hi.w = bfu2f(u[7]);
    ((float4*)dst)[0] = lo;
    ((float4*)dst)[1] = hi;
  }
  __syncthreads();

  const float scale = 0.1020620726f;  // 1/sqrt(96)
  for (int p = tid; p < 1024; p += 256) {
    int i = p >> 5, j = p & 31;
    float4 a4 = (float4){0.f, 0.f, 0.f, 0.f};
#pragma unroll
    for (int c = 0; c < 96; c += 4) {
      float4 a = *(const float4*)&sq[i * 100 + c];
      float4 b = *(const float4*)&sk[j * 100 + c];
      a4.x += a.x * b.x; a4.y += a.y * b.y; a4.z += a.z * b.z; a4.w += a.w * b.w;
    }
    ss[i * 36 + j] = (a4.x + a4.y + a4.z + a4.w) * scale;
  }
  __syncthreads();

  {
    int r = tid >> 3, g = tid & 7;
    float4 v = *(float4*)&ss[r * 36 + g * 4];
    float mx = fmaxf(fmaxf(v.x, v.y), fmaxf(v.z, v.w));
#pragma unroll
    for (int off = 1; off < 8; off <<= 1) mx = fmaxf(mx, __shfl_xor(mx, off, 64));
    v.x = __expf(v.x - mx); v.y = __expf(v.y - mx);
    v.z = __expf(v.z - mx); v.w = __expf(v.w - mx);
    float sum = v.x + v.y + v.z + v.w;
#pragma unroll
    for (int off = 1; off < 8; off <<= 1) sum += __shfl_xor(sum, off, 64);
    float inv = 1.f / sum;
    v.x *= inv; v.y *= inv; v.z *= inv; v.w *= inv;
    *(float4*)&ss[r * 36 + g * 4] = v;
  }
  __syncthreads();

  for (int p = tid; p < 768; p += 256) {
    int i = p / 24, c = (p % 24) * 4;
    float4 a = (float4){0.f, 0.f, 0.f, 0.f};
#pragma unroll
    for (int j = 0; j < 32; ++j) {
      float w = ss[i * 36 + j];
      float4 vv = *(const float4*)&sv[j * 100 + c];
      a.x += w * vv.x; a.y += w * vv.y; a.z += w * vv.z; a.w += w * vv.w;
    }
    ushort4 u;
    u.x = f2bfu(a.x); u.y = f2bfu(a.y); u.z = f2bfu(a.z); u.w = f2bfu(a.w);
    *(ushort4*)&z[((size_t)n * 32 + i) * 192 + head * 96 + c] = u;
  }
}

// ---------------------------------------------------------------------------
// LayerNorm: bf16 in -> bf16 out. 1 wave per row, 4 rows/block.
// ---------------------------------------------------------------------------
__global__ __launch_bounds__(256) void ln_kernel(
    const unsigned short* __restrict__ t, unsigned short* __restrict__ hb,
    const float* __restrict__ g, const float* __restrict__ b)
{
  const long row = (long)blockIdx.x * 4 + (threadIdx.x >> 6);
  const int lane = threadIdx.x & 63;
  const ushort4* p = (const ushort4*)(t + row * 768);
  float4 v[3];
  float s = 0.f, s2 = 0.f;
#pragma unroll
  for (int j = 0; j < 3; ++j) {
    ushort4 u = p[j * 64 + lane];
    float4 f;
    f.x = bfu2f(u.x); f.y = bfu2f(u.y); f.z = bfu2f(u.z); f.w = bfu2f(u.w);
    v[j] = f;
    s  += f.x + f.y + f.z + f.w;
    s2 += f.x * f.x + f.y * f.y + f.z * f.z + f.w * f.w;
  }
#pragma unroll
  for (int off = 32; off; off >>= 1) {
    s  += __shfl_xor(s, off, 64);
    s2 += __shfl_xor(s2, off, 64);
  }
  const float mean = s * (1.f / 768.f);
  const float var  = s2 * (1.f / 768.f) - mean * mean;
  const float rs   = rsqrtf(var + 1e-5f);
  ushort4* hbo = (ushort4*)(hb + row * 768);
#pragma unroll
  for (int j = 0; j < 3; ++j) {
    int idx = j * 64 + lane;
    float4 gg = ((const float4*)g)[idx];
    float4 bb = ((const float4*)b)[idx];
    ushort4 u;
    u.x = f2bfu((v[j].x - mean) * rs * gg.x + bb.x);
    u.y = f2bfu((v[j].y - mean) * rs * gg.y + bb.y);
    u.z = f2bfu((v[j].z - mean) * rs * gg.z + bb.z);
    u.w = f2bfu((v[j].w - mean) * rs * gg.w + bb.w);
    hbo[idx] = u;
  }
}

// ---------------------------------------------------------------------------
// Final LN + 2-col output projection. bf16 in, f32 out. 1 wave per row.
// ---------------------------------------------------------------------------
__global__ __launch_bounds__(256) void ln_out_kernel(
    const unsigned short* __restrict__ t, const float* __restrict__ g,
    const float* __restrict__ b, const float* __restrict__ Wo,
    const float* __restrict__ bo, float* __restrict__ out)
{
  const long row = (long)blockIdx.x * 4 + (threadIdx.x >> 6);
  const int lane = threadIdx.x & 63;
  const ushort4* p = (const ushort4*)(t + row * 768);
  float4 v[3];
  float s = 0.f, s2 = 0.f;
#pragma unroll
  for (int j = 0; j < 3; ++j) {
    ushort4 u = p[j * 64 + lane];
    float4 f;
    f.x = bfu2f(u.x); f.y = bfu2f(u.y); f.z = bfu2f(u.z); f.w = bfu2f(u.w);
    v[j] = f;
    s  += f.x + f.y + f.z + f.w;
    s2 += f.x * f.x + f.y * f.y + f.z * f.z + f.w * f.w;
  }
#pragma unroll
  for (int off = 32; off; off >>= 1) {
    s  += __shfl_xor(s, off, 64);
    s2 += __shfl_xor(s2, off, 64);
  }
  const float mean = s * (1.f / 768.f);
  const float var  = s2 * (1.f / 768.f) - mean * mean;
  const float rs   = rsqrtf(var + 1e-5f);
  float o0 = 0.f, o1 = 0.f;
#pragma unroll
  for (int j = 0; j < 3; ++j) {
    int idx = j * 64 + lane;
    float4 gg = ((const float4*)g)[idx];
    float4 bb = ((const float4*)b)[idx];
    float4 w0 = ((const float4*)Wo)[idx];
    float4 w1 = ((const float4*)(Wo + 768))[idx];
    float y;
    y = (v[j].x - mean) * rs * gg.x + bb.x; o0 += y * w0.x; o1 += y * w1.x;
    y = (v[j].y - mean) * rs * gg.y + bb.y; o0 += y * w0.y; o1 += y * w1.y;
    y = (v[j].z - mean) * rs * gg.z + bb.z; o0 += y * w0.z; o1 += y * w1.z;
    y = (v[j].w - mean) * rs * gg.w + bb.w; o0 += y * w0.w; o1 += y * w1.w;
  }
#pragma unroll
  for (int off = 32; off; off >>= 1) {
    o0 += __shfl_xor(o0, off, 64);
    o1 += __shfl_xor(o1, off, 64);
  }
  if (lane == 0) {
    out[row * 2 + 0] = o0 + bo[0];
    out[row * 2 + 1] = o1 + bo[1];
  }
}

// sentinel: workspace too small — diagnosable (error ~12345)
__global__ void sentinel_kernel(float* out) {
  if (threadIdx.x == 0 && blockIdx.x == 0) out[0] = 12345.0f;
}

// ---------------------------------------------------------------------------
extern "C" void kernel_launch(void* const* d_in, const int* in_sizes, int n_in,
                              void* d_out, int out_size, void* d_ws, size_t ws_size,
                              hipStream_t stream)
{
  const int*   ids = (const int*)  d_in[0];
  const float* emb = (const float*)d_in[1];
  const float* pos = (const float*)d_in[2];
  const float* Wk1 = (const float*)d_in[3];  const float* bk1 = (const float*)d_in[4];
  const float* Wv1 = (const float*)d_in[5];  const float* bv1 = (const float*)d_in[6];
  const float* Wq1 = (const float*)d_in[7];  const float* bq1 = (const float*)d_in[8];
  const float* Wk2 = (const float*)d_in[9];  const float* bk2 = (const float*)d_in[10];
  const float* Wv2 = (const float*)d_in[11]; const float* bv2 = (const float*)d_in[12];
  const float* Wq2 = (const float*)d_in[13]; const float* bq2 = (const float*)d_in[14];
  const float* Wp  = (const float*)d_in[15]; const float* bp  = (const float*)d_in[16];
  const float* g1  = (const float*)d_in[17]; const float* be1 = (const float*)d_in[18];
  const float* W1  = (const float*)d_in[19]; const float* bf1 = (const float*)d_in[20];
  const float* W2  = (const float*)d_in[21]; const float* bf2 = (const float*)d_in[22];
  const float* g2  = (const float*)d_in[23]; const float* be2 = (const float*)d_in[24];
  const float* Wo  = (const float*)d_in[25]; const float* bo  = (const float*)d_in[26];
  float* out = (float*)d_out;

  char* ws = (char*)d_ws;
  size_t off = 0;
  auto alloc = [&](size_t bytes) { void* p = ws + off; off += (bytes + 255) & ~(size_t)255; return p; };

  // weights (bf16) ~7.5 MiB
  unsigned short* Wqkv = (unsigned short*)alloc(768 * 768 * 2);
  float*          bqkv = (float*)         alloc(768 * 4);
  unsigned short* Wp_b = (unsigned short*)alloc(768 * 192 * 2);
  unsigned short* W1_b = (unsigned short*)alloc(2048 * 768 * 2);
  unsigned short* W2_b = (unsigned short*)alloc(768 * 2048 * 2);
  const size_t woff = off;

  // adaptive chunking: slabs SA(x->h), SB(qkv->t1->t2), SC(z->f), all bf16
  long R = NROWS; int C = 1; bool ok = false;
  for (;;) {
    size_t aA = (((size_t)R * 768 * 2) + 255) & ~(size_t)255;
    size_t aC = (((size_t)R * 2048 * 2) + 255) & ~(size_t)255;
    if (woff + 2 * aA + aC <= ws_size) { ok = true; break; }
    if (C == 256) break;
    C <<= 1; R >>= 1;
  }
  if (!ok) {
    sentinel_kernel<<<1, 64, 0, stream>>>(out);
    return;
  }
  const size_t aA = (((size_t)R * 768 * 2) + 255) & ~(size_t)255;
  unsigned short* SA = (unsigned short*)(ws + woff);
  unsigned short* SB = (unsigned short*)(ws + woff + aA);
  unsigned short* SC = (unsigned short*)(ws + woff + 2 * aA);

  // ---- 0. fused weight prep ----
  prep_kernel<<<(3883776 + 255) / 256, 256, 0, stream>>>(
      Wq1, Wk1, Wv1, Wq2, Wk2, Wv2, bq1, bk1, bv1, bq2, bk2, bv2,
      Wp, W1, W2, Wqkv, bqkv, Wp_b, W1_b, W2_b);

  for (int c = 0; c < C; ++c) {
    const long row0 = (long)c * R;
    // 1. embed -> SA (x bf16)
    embed_kernel<<<R / 4, 256, 0, stream>>>(ids + row0, emb, pos, SA);
    // 2. QKV (padded N=768): SB[R,768] = x @ Wqkv^T   (KT=12, even)
    gemm256<false, false><<<dim3(3, R / 256), 512, 0, stream>>>(
        SA, Wqkv, bqkv, nullptr, SB, 768, 768);
    // 3. attention -> SC (z bf16 [R,192])
    attn_kernel<<<dim3(R / 32, 2), 256, 0, stream>>>(SB, SC);
    // 4. proj + resid(x): SB[R,768] = z @ Wp^T + bp + x   (K=192 -> 128^2 kernel)
    gemm_bt<false, true><<<dim3(6, R / 128), 256, 0, stream>>>(
        SC, Wp_b, bp, SA, SB, 768, 192);
    // 5. LN1: SA = LN(SB)
    ln_kernel<<<R / 4, 256, 0, stream>>>(SB, SA, g1, be1);
    // 6. FFN1: SC[R,2048] = relu(h @ W1^T + bf1)   (KT=12)
    gemm256<true, false><<<dim3(8, R / 256), 512, 0, stream>>>(
        SA, W1_b, bf1, nullptr, SC, 2048, 768);
    // 7. FFN2 + resid(h): SB[R,768] = f @ W2^T + bf2 + h   (KT=32)
    gemm256<false, true><<<dim3(3, R / 256), 512, 0, stream>>>(
        SC, W2_b, bf2, SA, SB, 768, 2048);
    // 8. LN2 + output projection
    ln_out_kernel<<<R / 4, 256, 0, stream>>>(SB, g2, be2, Wo, bo, out + row0 * 2);
  }
}

// Round 10
// 1679.706 us; speedup vs baseline: 1.3604x; 1.0126x over previous
//
#include <hip/hip_runtime.h>
#include <hip/hip_bf16.h>

typedef __attribute__((ext_vector_type(8))) short short8;
typedef __attribute__((ext_vector_type(8))) unsigned short ushort8;
typedef __attribute__((ext_vector_type(4))) float f32x4;

#define NROWS 131072L   // N*T = 4096*32

__device__ __forceinline__ unsigned short f2bfu(float f) {
  union { float f; unsigned u; } a; a.f = f;
  unsigned r = a.u + 0x7fffu + ((a.u >> 16) & 1u);
  return (unsigned short)(r >> 16);
}
__device__ __forceinline__ float bfu2f(unsigned short u) {
  union { unsigned u; float f; } a; a.u = (unsigned)u << 16; return a.f;
}

__device__ __forceinline__ void llds16(const void* g, void* l) {
  __builtin_amdgcn_global_load_lds(
      (const __attribute__((address_space(1))) void*)g,
      (__attribute__((address_space(3))) void*)l, 16, 0, 0);
}

#define SBAR() asm volatile("s_barrier" ::: "memory")

// ---------------------------------------------------------------------------
// 256x256 8-phase GEMM (T2+T3+T4+T5): C[M,N] = A[M,K] * B[N,K]^T + bias
// 8 waves (2Mx4N), BK=64, half-tile staged dbuf LDS, XOR-swizzled ds_read,
// counted vmcnt(6) once per K-tile, setprio around MFMA clusters.
// R7: address arithmetic hoisted (XOR split into base pointers + imm offsets),
// K-loop unrolled x2 so dbuf parity is a literal.
// R9: coalesced epilogue — acc scattered into LDS [256][264] bf16 tile, then
// row-major ushort8 read-back + coalesced resid add + dwordx4 stores
// (replaces 128 scalar 2B stores + 128 scalar 2B resid loads per thread).
// Requires M%256==0, N%256==0, K%128==0 (KT even), K>=128.
// ---------------------------------------------------------------------------
template<bool RELU, bool RESID>
__global__ __launch_bounds__(512, 2) void gemm256(
    const unsigned short* __restrict__ A, const unsigned short* __restrict__ B,
    const float* __restrict__ bias, const unsigned short* __restrict__ resid,
    unsigned short* __restrict__ Cb, int N, int K)
{
  // staging: A bytes [0,65536), B bytes [65536,131072); epilogue reuses all
  // 135168 B as a [256][264] bf16 tile (stride 528 B: 16B-aligned, +4-bank/row)
  __shared__ unsigned short lds[67584];
  const int tid  = threadIdx.x;
  const int lane = tid & 63;
  const int wave = tid >> 6;    // 0..7
  const int wr = wave >> 2;     // 0..1
  const int wc = wave & 3;      // 0..3
  const int KT = K >> 6;

  // XCD-aware bijective swizzle (m204)
  const int gx  = gridDim.x;
  const int nwg = gx * gridDim.y;
  int bid = blockIdx.y * gx + blockIdx.x;
  {
    const int q = nwg >> 3, r = nwg & 7;
    const int xcd = bid & 7, i = bid >> 3;
    bid = (xcd < r ? xcd * (q + 1) : r * (q + 1) + (xcd - r) * q) + i;
  }
  const long brow = (long)(bid / gx) * 256;
  const long bcol = (long)(bid % gx) * 256;

  // ---- staging: thread's 2 linear LDS 16B-blocks, inverse-swizzled source
  const int i0  = wave * 128 + lane;        // 16B-block idx (issue 0); issue 1 = +64
  const int r0  = i0 >> 3;                  // source row within half (issue 1: +8)
  const int js0 = (i0 & 7) ^ (r0 & 7);      // inverse-swizzled 8-elem col chunk
  const int i0x16 = i0 * 16;                // LDS byte offset of issue-0 block
  char* Lb = (char*)lds;

  // precomputed global source bases (half0/half1 of A and B)
  const char* sA0 = (const char*)(A + (brow + r0) * (long)K + js0 * 8);
  const char* sA1 = sA0 + 256L * K;         // +128 rows (bytes)
  const char* sB0 = (const char*)(B + (bcol + r0) * (long)K + js0 * 8);
  const char* sB1 = sB0 + 256L * K;
  const long d8K = 16L * K;                 // issue-1 source delta (+8 rows, bytes)

  auto stage = [&](const char* srcBase, int s, int ldsByteOff) {
    const int kb = (s < KT ? s : KT - 1) << 7;   // K-tile byte offset (clamped)
    const char* p = srcBase + kb;
    char* dst = Lb + ldsByteOff + i0x16;
    llds16(p,       dst);
    llds16(p + d8K, dst + 1024);
  };

  // ---- reader base pointers: XOR pre-applied, loop-invariant
  const int wr16r = wr * 16 + (lane & 15);  // A row within half (+mi*32)
  const int wc16r = wc * 16 + (lane & 15);  // B row within half (+nn*64)
  const int ccol  = (lane >> 4) << 4;       // byte col within 64B kk-half
  const int swz   = (lane & 7) << 4;        // XOR bits 4-6
  const int kx0 = (0  + ccol) ^ swz;        // kk=0 within-row byte (swizzled)
  const int kx1 = (64 + ccol) ^ swz;        // kk=1
  const char* pA0 = (const char*)lds + wr16r * 128 + kx0;
  const char* pA1 = (const char*)lds + wr16r * 128 + kx1;
  const char* pB0 = (const char*)lds + 65536 + wc16r * 128 + kx0;
  const char* pB1 = (const char*)lds + 65536 + wc16r * 128 + kx1;

#define RDA(D, H)                                                            \
  _Pragma("unroll") for (int mi = 0; mi < 4; ++mi) {                         \
    af[mi][0] = *(const short8*)(pA0 + (((D)*2+(H)) * 16384 + mi * 4096));   \
    af[mi][1] = *(const short8*)(pA1 + (((D)*2+(H)) * 16384 + mi * 4096));   \
  }
#define RDB(D, H, NB)                                                        \
  _Pragma("unroll") for (int nn = 0; nn < 2; ++nn) {                         \
    bf[(NB)*2+nn][0] = *(const short8*)(pB0 + (((D)*2+(H)) * 16384 + nn * 8192)); \
    bf[(NB)*2+nn][1] = *(const short8*)(pB1 + (((D)*2+(H)) * 16384 + nn * 8192)); \
  }
#define MFMA_Q(qa, qb)                                                       \
  __builtin_amdgcn_s_setprio(1);                                             \
  _Pragma("unroll") for (int mi = 0; mi < 4; ++mi)                           \
  _Pragma("unroll") for (int nn = 0; nn < 2; ++nn)                           \
  _Pragma("unroll") for (int kk = 0; kk < 2; ++kk)                           \
    acc[(qa)*4+mi][(qb)*2+nn] = __builtin_amdgcn_mfma_f32_16x16x32_bf16(     \
        af[mi][kk], bf[(qb)*2+nn][kk], acc[(qa)*4+mi][(qb)*2+nn], 0,0,0);    \
  __builtin_amdgcn_s_setprio(0);

// one K-tile, dbuf parity D as literal; stage targets per original schedule
#define KTILE(D, T)                                                          \
  {                                                                          \
    short8 af[4][2], bf[4][2];                                               \
    /* ph1: read A0,B0 ; stage A-half1(t+1) into other dbuf */               \
    RDA(D, 0)                                                                \
    RDB(D, 0, 0)                                                             \
    stage(sA1, (T) + 1, (((D)^1) * 2 + 1) * 16384);                          \
    asm volatile("s_waitcnt lgkmcnt(8)" ::: "memory");                       \
    SBAR();                                                                  \
    MFMA_Q(0, 0)                                                             \
    SBAR();                                                                  \
    /* ph2: read B1 ; stage A-half0(t+2) (this dbuf, read done in ph1) */    \
    RDB(D, 1, 1)                                                             \
    stage(sA0, (T) + 2, ((D) * 2 + 0) * 16384);                              \
    SBAR();                                                                  \
    MFMA_Q(0, 1)                                                             \
    SBAR();                                                                  \
    /* ph3: read A1 ; stage B-half0(t+2) */                                  \
    RDA(D, 1)                                                                \
    stage(sB0, (T) + 2, 65536 + ((D) * 2 + 0) * 16384);                      \
    SBAR();                                                                  \
    MFMA_Q(1, 0)                                                             \
    SBAR();                                                                  \
    /* ph4: stage B-half1(t+2) */                                            \
    stage(sB1, (T) + 2, 65536 + ((D) * 2 + 1) * 16384);                      \
    SBAR();                                                                  \
    MFMA_Q(1, 1)                                                             \
    asm volatile("s_waitcnt vmcnt(6)" ::: "memory");                         \
    SBAR();                                                                  \
  }

  f32x4 acc[8][4];
#pragma unroll
  for (int i = 0; i < 8; ++i)
#pragma unroll
    for (int n = 0; n < 4; ++n)
      acc[i][n] = (f32x4){0.f, 0.f, 0.f, 0.f};

  // ---- prologue: tile0 (A0,B0,A1,B1) + tile1 (A0,B0,B1); A1(t1) in t0/ph1
  stage(sA0, 0, 0 * 16384);
  stage(sB0, 0, 65536 + 0 * 16384);
  stage(sA1, 0, 1 * 16384);
  stage(sB1, 0, 65536 + 1 * 16384);
  stage(sA0, 1, 2 * 16384);
  stage(sB0, 1, 65536 + 2 * 16384);
  stage(sB1, 1, 65536 + 3 * 16384);
  asm volatile("s_waitcnt vmcnt(6)" ::: "memory");   // tile0 resident
  SBAR();

  for (int t = 0; t < KT; t += 2) {
    KTILE(0, t)
    KTILE(1, t + 1)
  }

  // ---- epilogue (R9: coalesced via LDS transpose) ----
  // drain in-flight clamped prefetches (they DMA into the staging LDS we are
  // about to overwrite) — every wave drains, then barrier.
  asm volatile("s_waitcnt vmcnt(0)" ::: "memory");
  SBAR();

  const int fr = lane & 15;
  const int fq = lane >> 4;
  // phase 1: scatter bf16(acc + bias [,relu]) into E[256][264]
#pragma unroll
  for (int n = 0; n < 4; ++n) {
    const int cloc = n * 64 + wc * 16 + fr;
    const float bv = bias[bcol + cloc];
#pragma unroll
    for (int i = 0; i < 8; ++i) {
      const int rloc = i * 32 + wr * 16 + fq * 4;
#pragma unroll
      for (int r2 = 0; r2 < 4; ++r2) {
        float v = acc[i][n][r2] + bv;
        if (RELU) v = fmaxf(v, 0.f);
        lds[(rloc + r2) * 264 + cloc] = f2bfu(v);
      }
    }
  }
  SBAR();

  // phase 2: row-major coalesced read-back + resid + dwordx4 store
#pragma unroll
  for (int it = 0; it < 16; ++it) {
    const int idx  = it * 512 + tid;     // 0..8191
    const int rloc = idx >> 5;           // 0..255
    const int cb   = (idx & 31) * 8;     // col block (8 bf16 = 16B)
    ushort8 u = *(const ushort8*)(lds + rloc * 264 + cb);
    const long row = brow + rloc;
    unsigned short* dst = Cb + row * (long)N + bcol + cb;
    if (RESID) {
      const ushort8 rv = *(const ushort8*)(resid + row * (long)N + bcol + cb);
#pragma unroll
      for (int e = 0; e < 8; ++e)
        u[e] = f2bfu(bfu2f(u[e]) + bfu2f(rv[e]));
    }
    *(ushort8*)dst = u;
  }
#undef RDA
#undef RDB
#undef MFMA_Q
#undef KTILE
}

// ---------------------------------------------------------------------------
// 128x128 m97-structure GEMM (kept for proj: K=192). C = A*B^T + bias (+resid)
// ---------------------------------------------------------------------------
template<bool RELU, bool RESID>
__global__ __launch_bounds__(256) void gemm_bt(
    const unsigned short* __restrict__ A, const unsigned short* __restrict__ B,
    const float* __restrict__ bias, const unsigned short* __restrict__ resid,
    unsigned short* __restrict__ Cb, int N, int K)
{
  __shared__ unsigned short lds_a[128 * 64];
  __shared__ unsigned short lds_b[128 * 64];
  const int tid  = threadIdx.x;
  const int lane = tid & 63;
  const int wave = tid >> 6;
  const int wr = wave >> 1, wc = wave & 1;

  const int gx  = gridDim.x;
  const int nwg = gx * gridDim.y;
  int bid = blockIdx.y * gx + blockIdx.x;
  {
    const int q = nwg >> 3, r = nwg & 7;
    const int xcd = bid & 7, i = bid >> 3;
    bid = (xcd < r ? xcd * (q + 1) : r * (q + 1) + (xcd - r) * q) + i;
  }
  const long brow = (long)(bid / gx) * 128;
  const long bcol = (long)(bid % gx) * 128;

  f32x4 acc[4][4];
#pragma unroll
  for (int m = 0; m < 4; ++m)
#pragma unroll
    for (int n = 0; n < 4; ++n)
      acc[m][n] = (f32x4){0.f, 0.f, 0.f, 0.f};

  const int srow = tid >> 3;
  const int scol = (tid & 7) * 8;

  for (int k0 = 0; k0 < K; k0 += 64) {
#pragma unroll
    for (int i = 0; i < 4; ++i) {
      int r = i * 32 + srow;
      llds16(A + (brow + r) * (long)K + k0 + scol, lds_a + r * 64 + scol);
    }
#pragma unroll
    for (int i = 0; i < 4; ++i) {
      int r = i * 32 + srow;
      llds16(B + (bcol + r) * (long)K + k0 + scol, lds_b + r * 64 + scol);
    }
    asm volatile("s_waitcnt vmcnt(0)" ::: "memory");
    __syncthreads();

#pragma unroll
    for (int ks = 0; ks < 2; ++ks) {
      short8 af[4], bfr[4];
#pragma unroll
      for (int m = 0; m < 4; ++m)
        af[m] = *(const short8*)(lds_a + (wr*64 + m*16 + (lane & 15))*64 + ks*32 + (lane >> 4)*8);
#pragma unroll
      for (int n = 0; n < 4; ++n)
        bfr[n] = *(const short8*)(lds_b + (wc*64 + n*16 + (lane & 15))*64 + ks*32 + (lane >> 4)*8);
#pragma unroll
      for (int m = 0; m < 4; ++m)
#pragma unroll
        for (int n = 0; n < 4; ++n)
          acc[m][n] = __builtin_amdgcn_mfma_f32_16x16x32_bf16(af[m], bfr[n], acc[m][n], 0, 0, 0);
    }
    __syncthreads();
  }

  const int fr = lane & 15;
  const int fq = lane >> 4;
#pragma unroll
  for (int m = 0; m < 4; ++m) {
#pragma unroll
    for (int n = 0; n < 4; ++n) {
      long col = bcol + wc*64 + n*16 + fr;
      float bv = bias[col];
#pragma unroll
      for (int r2 = 0; r2 < 4; ++r2) {
        long row = brow + wr*64 + m*16 + fq*4 + r2;
        float v = acc[m][n][r2] + bv;
        if (RESID) v += bfu2f(resid[row * N + col]);
        if (RELU)  v = fmaxf(v, 0.f);
        Cb[row * N + col] = f2bfu(v);
      }
    }
  }
}

// ---------------------------------------------------------------------------
// Fused weight prep. Virtual layout:
// [Wqkv 768*768][bqkv 768][Wp 147456][W1 1572864][W2 1572864] = 3883776
// Wqkv rows: q1 k1 v1 q2 k2 v2 (96 each) + 192 zero rows.
// ---------------------------------------------------------------------------
__global__ __launch_bounds__(256) void prep_kernel(
    const float* __restrict__ Wq1, const float* __restrict__ Wk1, const float* __restrict__ Wv1,
    const float* __restrict__ Wq2, const float* __restrict__ Wk2, const float* __restrict__ Wv2,
    const float* __restrict__ bq1, const float* __restrict__ bk1, const float* __restrict__ bv1,
    const float* __restrict__ bq2, const float* __restrict__ bk2, const float* __restrict__ bv2,
    const float* __restrict__ Wp, const float* __restrict__ W1, const float* __restrict__ W2,
    unsigned short* __restrict__ Wqkv, float* __restrict__ bqkv,
    unsigned short* __restrict__ Wp_b, unsigned short* __restrict__ W1_b,
    unsigned short* __restrict__ W2_b)
{
  long i = (long)blockIdx.x * 256 + threadIdx.x;
  if (i >= 3883776L) return;
  if (i < 589824) {
    int row = (int)(i / 768), col = (int)(i % 768);
    float v = 0.f;
    if (row < 576) {
      int which = row / 96, r = row % 96;
      const float* s = which == 0 ? Wq1 : which == 1 ? Wk1 : which == 2 ? Wv1
                     : which == 3 ? Wq2 : which == 4 ? Wk2 : Wv2;
      v = s[r * 768 + col];
    }
    Wqkv[i] = f2bfu(v);
    return;
  }
  i -= 589824;
  if (i < 768) {
    float v = 0.f;
    if (i < 576) {
      int which = (int)(i / 96), r = (int)(i % 96);
      const float* s = which == 0 ? bq1 : which == 1 ? bk1 : which == 2 ? bv1
                     : which == 3 ? bq2 : which == 4 ? bk2 : bv2;
      v = s[r];
    }
    bqkv[i] = v;
    return;
  }
  i -= 768;
  if (i < 147456) { Wp_b[i] = f2bfu(Wp[i]); return; }
  i -= 147456;
  if (i < 1572864) { W1_b[i] = f2bfu(W1[i]); return; }
  i -= 1572864;
  W2_b[i] = f2bfu(W2[i]);
}

// ---------------------------------------------------------------------------
// embed: xb = bf16(emb[ids] + pos). 4 rows/block, 1 wave/row.
// ---------------------------------------------------------------------------
__global__ __launch_bounds__(256) void embed_kernel(
    const int* __restrict__ ids, const float* __restrict__ emb,
    const float* __restrict__ pos, unsigned short* __restrict__ xb)
{
  const long row  = (long)blockIdx.x * 4 + (threadIdx.x >> 6);
  const int lane = threadIdx.x & 63;
  const int tok  = ids[row];
  const int tp   = (int)(row & 31);
  const float4* e = (const float4*)(emb + (size_t)tok * 768);
  const float4* p = (const float4*)(pos + (size_t)tp * 768);
  ushort4* bo = (ushort4*)(xb + row * 768);
#pragma unroll
  for (int j = 0; j < 3; ++j) {
    int idx = j * 64 + lane;
    float4 v = e[idx];
    float4 q = p[idx];
    v.x += q.x; v.y += q.y; v.z += q.z; v.w += q.w;
    ushort4 u;
    u.x = f2bfu(v.x); u.y = f2bfu(v.y); u.z = f2bfu(v.z); u.w = f2bfu(v.w);
    bo[idx] = u;
  }
}

// ---------------------------------------------------------------------------
// attention: one block per (seq, head). qkv bf16 [rows][768],
// row cols: [q1 k1 v1 q2 k2 v2 pad] each 96.  z out bf16 [rows][192].
// ---------------------------------------------------------------------------
__global__ __launch_bounds__(256) void attn_kernel(
    const unsigned short* __restrict__ qkv, unsigned short* __restrict__ z)
{
  const int n = blockIdx.x, head = blockIdx.y;
  __shared__ float sq[32 * 100];
  __shared__ float sk[32 * 100];
  __shared__ float sv[32 * 100];
  __shared__ float ss[32 * 36];
  const unsigned short* base = qkv + (size_t)n * 32 * 768 + head * 288;
  const int tid = threadIdx.x;

  for (int p = tid; p < 1152; p += 256) {
    int m = p / 384, q = p % 384, r = q / 12, c = (q % 12) * 8;
    ushort8 u = *(const ushort8*)(base + (size_t)r * 768 + m * 96 + c);
    float* dst = (m == 0 ? sq : m == 1 ? sk : sv) + r * 100 + c;
    float4 lo, hi;
    lo.x = bfu2f(u[0]); lo.y = bfu2f(u[1]); lo.z = bfu2f(u[2]); lo.w = bfu2f(u[3]);
    hi.x = bfu2f(u[4]); hi.y = bfu2f(u[5]); hi.z = bfu2f(u[6]); hi.w = bfu2f(u[7]);
    ((float4*)dst)[0] = lo;
    ((float4*)dst)[1] = hi;
  }
  __syncthreads();

  const float scale = 0.1020620726f;  // 1/sqrt(96)
  for (int p = tid; p < 1024; p += 256) {
    int i = p >> 5, j = p & 31;
    float4 a4 = (float4){0.f, 0.f, 0.f, 0.f};
#pragma unroll
    for (int c = 0; c < 96; c += 4) {
      float4 a = *(const float4*)&sq[i * 100 + c];
      float4 b = *(const float4*)&sk[j * 100 + c];
      a4.x += a.x * b.x; a4.y += a.y * b.y; a4.z += a.z * b.z; a4.w += a.w * b.w;
    }
    ss[i * 36 + j] = (a4.x + a4.y + a4.z + a4.w) * scale;
  }
  __syncthreads();

  {
    int r = tid >> 3, g = tid & 7;
    float4 v = *(float4*)&ss[r * 36 + g * 4];
    float mx = fmaxf(fmaxf(v.x, v.y), fmaxf(v.z, v.w));
#pragma unroll
    for (int off = 1; off < 8; off <<= 1) mx = fmaxf(mx, __shfl_xor(mx, off, 64));
    v.x = __expf(v.x - mx); v.y = __expf(v.y - mx);
    v.z = __expf(v.z - mx); v.w = __expf(v.w - mx);
    float sum = v.x + v.y + v.z + v.w;
#pragma unroll
    for (int off = 1; off < 8; off <<= 1) sum += __shfl_xor(sum, off, 64);
    float inv = 1.f / sum;
    v.x *= inv; v.y *= inv; v.z *= inv; v.w *= inv;
    *(float4*)&ss[r * 36 + g * 4] = v;
  }
  __syncthreads();

  for (int p = tid; p < 768; p += 256) {
    int i = p / 24, c = (p % 24) * 4;
    float4 a = (float4){0.f, 0.f, 0.f, 0.f};
#pragma unroll
    for (int j = 0; j < 32; ++j) {
      float w = ss[i * 36 + j];
      float4 vv = *(const float4*)&sv[j * 100 + c];
      a.x += w * vv.x; a.y += w * vv.y; a.z += w * vv.z; a.w += w * vv.w;
    }
    ushort4 u;
    u.x = f2bfu(a.x); u.y = f2bfu(a.y); u.z = f2bfu(a.z); u.w = f2bfu(a.w);
    *(ushort4*)&z[((size_t)n * 32 + i) * 192 + head * 96 + c] = u;
  }
}

// ---------------------------------------------------------------------------
// LayerNorm: bf16 in -> bf16 out. 1 wave per row, 4 rows/block.
// ---------------------------------------------------------------------------
__global__ __launch_bounds__(256) void ln_kernel(
    const unsigned short* __restrict__ t, unsigned short* __restrict__ hb,
    const float* __restrict__ g, const float* __restrict__ b)
{
  const long row = (long)blockIdx.x * 4 + (threadIdx.x >> 6);
  const int lane = threadIdx.x & 63;
  const ushort4* p = (const ushort4*)(t + row * 768);
  float4 v[3];
  float s = 0.f, s2 = 0.f;
#pragma unroll
  for (int j = 0; j < 3; ++j) {
    ushort4 u = p[j * 64 + lane];
    float4 f;
    f.x = bfu2f(u.x); f.y = bfu2f(u.y); f.z = bfu2f(u.z); f.w = bfu2f(u.w);
    v[j] = f;
    s  += f.x + f.y + f.z + f.w;
    s2 += f.x * f.x + f.y * f.y + f.z * f.z + f.w * f.w;
  }
#pragma unroll
  for (int off = 32; off; off >>= 1) {
    s  += __shfl_xor(s, off, 64);
    s2 += __shfl_xor(s2, off, 64);
  }
  const float mean = s * (1.f / 768.f);
  const float var  = s2 * (1.f / 768.f) - mean * mean;
  const float rs   = rsqrtf(var + 1e-5f);
  ushort4* hbo = (ushort4*)(hb + row * 768);
#pragma unroll
  for (int j = 0; j < 3; ++j) {
    int idx = j * 64 + lane;
    float4 gg = ((const float4*)g)[idx];
    float4 bb = ((const float4*)b)[idx];
    ushort4 u;
    u.x = f2bfu((v[j].x - mean) * rs * gg.x + bb.x);
    u.y = f2bfu((v[j].y - mean) * rs * gg.y + bb.y);
    u.z = f2bfu((v[j].z - mean) * rs * gg.z + bb.z);
    u.w = f2bfu((v[j].w - mean) * rs * gg.w + bb.w);
    hbo[idx] = u;
  }
}

// ---------------------------------------------------------------------------
// Final LN + 2-col output projection. bf16 in, f32 out. 1 wave per row.
// ---------------------------------------------------------------------------
__global__ __launch_bounds__(256) void ln_out_kernel(
    const unsigned short* __restrict__ t, const float* __restrict__ g,
    const float* __restrict__ b, const float* __restrict__ Wo,
    const float* __restrict__ bo, float* __restrict__ out)
{
  const long row = (long)blockIdx.x * 4 + (threadIdx.x >> 6);
  const int lane = threadIdx.x & 63;
  const ushort4* p = (const ushort4*)(t + row * 768);
  float4 v[3];
  float s = 0.f, s2 = 0.f;
#pragma unroll
  for (int j = 0; j < 3; ++j) {
    ushort4 u = p[j * 64 + lane];
    float4 f;
    f.x = bfu2f(u.x); f.y = bfu2f(u.y); f.z = bfu2f(u.z); f.w = bfu2f(u.w);
    v[j] = f;
    s  += f.x + f.y + f.z + f.w;
    s2 += f.x * f.x + f.y * f.y + f.z * f.z + f.w * f.w;
  }
#pragma unroll
  for (int off = 32; off; off >>= 1) {
    s  += __shfl_xor(s, off, 64);
    s2 += __shfl_xor(s2, off, 64);
  }
  const float mean = s * (1.f / 768.f);
  const float var  = s2 * (1.f / 768.f) - mean * mean;
  const float rs   = rsqrtf(var + 1e-5f);
  float o0 = 0.f, o1 = 0.f;
#pragma unroll
  for (int j = 0; j < 3; ++j) {
    int idx = j * 64 + lane;
    float4 gg = ((const float4*)g)[idx];
    float4 bb = ((const float4*)b)[idx];
    float4 w0 = ((const float4*)Wo)[idx];
    float4 w1 = ((const float4*)(Wo + 768))[idx];
    float y;
    y = (v[j].x - mean) * rs * gg.x + bb.x; o0 += y * w0.x; o1 += y * w1.x;
    y = (v[j].y - mean) * rs * gg.y + bb.y; o0 += y * w0.y; o1 += y * w1.y;
    y = (v[j].z - mean) * rs * gg.z + bb.z; o0 += y * w0.z; o1 += y * w1.z;
    y = (v[j].w - mean) * rs * gg.w + bb.w; o0 += y * w0.w; o1 += y * w1.w;
  }
#pragma unroll
  for (int off = 32; off; off >>= 1) {
    o0 += __shfl_xor(o0, off, 64);
    o1 += __shfl_xor(o1, off, 64);
  }
  if (lane == 0) {
    out[row * 2 + 0] = o0 + bo[0];
    out[row * 2 + 1] = o1 + bo[1];
  }
}

// sentinel: workspace too small — diagnosable (error ~12345)
__global__ void sentinel_kernel(float* out) {
  if (threadIdx.x == 0 && blockIdx.x == 0) out[0] = 12345.0f;
}

// ---------------------------------------------------------------------------
extern "C" void kernel_launch(void* const* d_in, const int* in_sizes, int n_in,
                              void* d_out, int out_size, void* d_ws, size_t ws_size,
                              hipStream_t stream)
{
  const int*   ids = (const int*)  d_in[0];
  const float* emb = (const float*)d_in[1];
  const float* pos = (const float*)d_in[2];
  const float* Wk1 = (const float*)d_in[3];  const float* bk1 = (const float*)d_in[4];
  const float* Wv1 = (const float*)d_in[5];  const float* bv1 = (const float*)d_in[6];
  const float* Wq1 = (const float*)d_in[7];  const float* bq1 = (const float*)d_in[8];
  const float* Wk2 = (const float*)d_in[9];  const float* bk2 = (const float*)d_in[10];
  const float* Wv2 = (const float*)d_in[11]; const float* bv2 = (const float*)d_in[12];
  const float* Wq2 = (const float*)d_in[13]; const float* bq2 = (const float*)d_in[14];
  const float* Wp  = (const float*)d_in[15]; const float* bp  = (const float*)d_in[16];
  const float* g1  = (const float*)d_in[17]; const float* be1 = (const float*)d_in[18];
  const float* W1  = (const float*)d_in[19]; const float* bf1 = (const float*)d_in[20];
  const float* W2  = (const float*)d_in[21]; const float* bf2 = (const float*)d_in[22];
  const float* g2  = (const float*)d_in[23]; const float* be2 = (const float*)d_in[24];
  const float* Wo  = (const float*)d_in[25]; const float* bo  = (const float*)d_in[26];
  float* out = (float*)d_out;

  char* ws = (char*)d_ws;
  size_t off = 0;
  auto alloc = [&](size_t bytes) { void* p = ws + off; off += (bytes + 255) & ~(size_t)255; return p; };

  // weights (bf16) ~7.5 MiB
  unsigned short* Wqkv = (unsigned short*)alloc(768 * 768 * 2);
  float*          bqkv = (float*)         alloc(768 * 4);
  unsigned short* Wp_b = (unsigned short*)alloc(768 * 192 * 2);
  unsigned short* W1_b = (unsigned short*)alloc(2048 * 768 * 2);
  unsigned short* W2_b = (unsigned short*)alloc(768 * 2048 * 2);
  const size_t woff = off;

  // adaptive chunking: slabs SA(x->h), SB(qkv->t1->t2), SC(z->f), all bf16
  long R = NROWS; int C = 1; bool ok = false;
  for (;;) {
    size_t aA = (((size_t)R * 768 * 2) + 255) & ~(size_t)255;
    size_t aC = (((size_t)R * 2048 * 2) + 255) & ~(size_t)255;
    if (woff + 2 * aA + aC <= ws_size) { ok = true; break; }
    if (C == 256) break;
    C <<= 1; R >>= 1;
  }
  if (!ok) {
    sentinel_kernel<<<1, 64, 0, stream>>>(out);
    return;
  }
  const size_t aA = (((size_t)R * 768 * 2) + 255) & ~(size_t)255;
  unsigned short* SA = (unsigned short*)(ws + woff);
  unsigned short* SB = (unsigned short*)(ws + woff + aA);
  unsigned short* SC = (unsigned short*)(ws + woff + 2 * aA);

  // ---- 0. fused weight prep ----
  prep_kernel<<<(3883776 + 255) / 256, 256, 0, stream>>>(
      Wq1, Wk1, Wv1, Wq2, Wk2, Wv2, bq1, bk1, bv1, bq2, bk2, bv2,
      Wp, W1, W2, Wqkv, bqkv, Wp_b, W1_b, W2_b);

  for (int c = 0; c < C; ++c) {
    const long row0 = (long)c * R;
    // 1. embed -> SA (x bf16)
    embed_kernel<<<R / 4, 256, 0, stream>>>(ids + row0, emb, pos, SA);
    // 2. QKV (padded N=768): SB[R,768] = x @ Wqkv^T   (KT=12, even)
    gemm256<false, false><<<dim3(3, R / 256), 512, 0, stream>>>(
        SA, Wqkv, bqkv, nullptr, SB, 768, 768);
    // 3. attention -> SC (z bf16 [R,192])
    attn_kernel<<<dim3(R / 32, 2), 256, 0, stream>>>(SB, SC);
    // 4. proj + resid(x): SB[R,768] = z @ Wp^T + bp + x   (K=192 -> 128^2 kernel)
    gemm_bt<false, true><<<dim3(6, R / 128), 256, 0, stream>>>(
        SC, Wp_b, bp, SA, SB, 768, 192);
    // 5. LN1: SA = LN(SB)
    ln_kernel<<<R / 4, 256, 0, stream>>>(SB, SA, g1, be1);
    // 6. FFN1: SC[R,2048] = relu(h @ W1^T + bf1)   (KT=12)
    gemm256<true, false><<<dim3(8, R / 256), 512, 0, stream>>>(
        SA, W1_b, bf1, nullptr, SC, 2048, 768);
    // 7. FFN2 + resid(h): SB[R,768] = f @ W2^T + bf2 + h   (KT=32)
    gemm256<false, true><<<dim3(3, R / 256), 512, 0, stream>>>(
        SC, W2_b, bf2, SA, SB, 768, 2048);
    // 8. LN2 + output projection
    ln_out_kernel<<<R / 4, 256, 0, stream>>>(SB, g2, be2, Wo, bo, out + row0 * 2);
  }
}